// Round 2
// baseline (1637.374 us; speedup 1.0000x reference)
//
#include <hip/hip_runtime.h>
#include <math.h>

// Problem constants (from reference)
#define T_WIN   3
#define N_NODES 50000
#define HID     128
#define E_PER_T 100000
#define NH      8
#define DK      16
#define CAP     64   // per-node LDS logit cache (avg total degree ~6; slow path covers overflow)

// R6: fills (harness ws poison) dominate top-5; owned time was spread over 23
// dispatches with att-buffer HBM round-trips (4 passes) and hat rw per agg
// chunk. Fused per-node attention (logits+softmax+agg in one wave pass,
// LDS logit cache), FFN now emits out0/1/2 directly (combine deleted),
// all 9 projections in one dispatch. 23 -> 17 dispatches.

typedef unsigned short u16;
typedef __attribute__((ext_vector_type(8))) short bf16x8;   // 8 bf16 = 4 VGPR
typedef __attribute__((ext_vector_type(4))) float f32x4;

__device__ __forceinline__ u16 f2bf(float v) {              // RNE f32->bf16
    unsigned u = __float_as_uint(v);
    return (u16)((u + 0x7fffu + ((u >> 16) & 1u)) >> 16);
}
__device__ __forceinline__ float bf2f(u16 u) {
    return __uint_as_float(((unsigned)u) << 16);
}
__device__ __forceinline__ f32x4 mfma16(bf16x8 a, bf16x8 b, f32x4 c) {
    return __builtin_amdgcn_mfma_f32_16x16x32_bf16(a, b, c, 0, 0, 0);
}

// ---------------------------------------------------------------------------
// Weight prep: transposed bf16 copies; wsplit also emits lo residual for
// fp32-equivalent split-MFMA. dst layout [C][R] (K contiguous).
// ---------------------------------------------------------------------------
__global__ __launch_bounds__(256) void wsplit_kernel(
    const float* __restrict__ src, u16* __restrict__ hi, u16* __restrict__ lo,
    int R, int C)
{
    int i = blockIdx.x * 256 + threadIdx.x;
    if (i >= R * C) return;
    int r = i / C, c = i - r * C;
    float v = src[i];
    u16 h = f2bf(v);
    hi[c * R + r] = h;
    lo[c * R + r] = f2bf(v - bf2f(h));
}

__global__ __launch_bounds__(256) void wt_kernel(
    const float* __restrict__ src, u16* __restrict__ dst, int R, int C)
{
    int i = blockIdx.x * 256 + threadIdx.x;
    if (i >= R * C) return;
    int r = i / C, c = i - r * C;
    dst[c * R + r] = f2bf(src[i]);
}

// ---------------------------------------------------------------------------
// CSR build (once). srcbuf stores SOURCE node ids in CSR order (no edge-id
// indirection needed anymore).
// ---------------------------------------------------------------------------
__global__ __launch_bounds__(256) void zero_counts_kernel(int* cursor)
{
    int i = blockIdx.x * 256 + threadIdx.x;
    if (i < T_WIN * N_NODES) cursor[i] = 0;
}

__global__ __launch_bounds__(256) void hist_kernel(
    const int* __restrict__ ei, int* counts)
{
    int i = blockIdx.x * 256 + threadIdx.x;
    if (i >= T_WIN * E_PER_T) return;
    int ts = i / E_PER_T;
    int e  = i - ts * E_PER_T;
    int tar = ei[(ts * 2 + 1) * E_PER_T + e];
    atomicAdd(&counts[ts * N_NODES + tar], 1);
}

__global__ __launch_bounds__(1024) void scan_kernel(
    const int* __restrict__ counts, int* __restrict__ offs)
{
    __shared__ int buf[1024];
    __shared__ int carry;
    const int ts = blockIdx.x;
    const int tid = threadIdx.x;
    if (tid == 0) carry = 0;
    __syncthreads();
    for (int base = 0; base < N_NODES; base += 1024) {
        int i = base + tid;
        int v = (i < N_NODES) ? counts[ts * N_NODES + i] : 0;
        buf[tid] = v;
        __syncthreads();
        for (int o = 1; o < 1024; o <<= 1) {
            int t = (tid >= o) ? buf[tid - o] : 0;
            __syncthreads();
            buf[tid] += t;
            __syncthreads();
        }
        int incl = buf[tid];
        if (i < N_NODES) offs[ts * (N_NODES + 1) + i] = carry + incl - v;
        __syncthreads();
        if (tid == 1023) carry += incl;
        __syncthreads();
    }
    if (tid == 0) offs[ts * (N_NODES + 1) + N_NODES] = carry;
}

__global__ __launch_bounds__(256) void copy_cursor_kernel(
    const int* __restrict__ offs, int* cursor)
{
    int i = blockIdx.x * 256 + threadIdx.x;
    if (i >= T_WIN * N_NODES) return;
    int ts = i / N_NODES;
    int n  = i - ts * N_NODES;
    cursor[i] = offs[ts * (N_NODES + 1) + n];
}

__global__ __launch_bounds__(256) void fill_kernel(
    const int* __restrict__ ei, int* cursor, int* __restrict__ srcbuf)
{
    int i = blockIdx.x * 256 + threadIdx.x;
    if (i >= T_WIN * E_PER_T) return;
    int ts = i / E_PER_T;
    int e  = i - ts * E_PER_T;
    int src = ei[(ts * 2) * E_PER_T + e];
    int tar = ei[(ts * 2 + 1) * E_PER_T + e];
    int pos = atomicAdd(&cursor[ts * N_NODES + tar], 1);
    srcbuf[ts * E_PER_T + pos] = src;
}

// ---------------------------------------------------------------------------
// Split-bf16 MFMA projection, ALL 9 (mat x ts) in one dispatch.
// blockIdx.y: ts = y/3, mat = y%3 (0=Q,1=K,2=V).
// ---------------------------------------------------------------------------
__global__ __launch_bounds__(256) void project_all_kernel(
    const float* __restrict__ x,
    const u16* __restrict__ QTh, const u16* __restrict__ QTl, const float* __restrict__ bq,
    const u16* __restrict__ KTh, const u16* __restrict__ KTl, const float* __restrict__ bk,
    const u16* __restrict__ VTh, const u16* __restrict__ VTl, const float* __restrict__ bv,
    u16* __restrict__ Qall, u16* __restrict__ Kall, u16* __restrict__ Vall)
{
    const int p  = blockIdx.y;
    const int ts = p / 3, mat = p - ts * 3;
    const u16 *WTh, *WTl; const float* b; u16* O;
    if (mat == 0)      { WTh = QTh; WTl = QTl; b = bq; O = Qall; }
    else if (mat == 1) { WTh = KTh; WTl = KTl; b = bk; O = Kall; }
    else               { WTh = VTh; WTl = VTl; b = bv; O = Vall; }
    const size_t NHID = (size_t)N_NODES * HID;
    const float* __restrict__ xs = x + (size_t)ts * NHID;
    O += (size_t)ts * NHID;

    __shared__ u16 xhS[64 * 128];
    __shared__ u16 xlS[64 * 128];
    const int tid = threadIdx.x;
    const int n0 = blockIdx.x * 64;

    {   // stage: 4 threads/row, each covers 32 cols; hi/lo split, swizzled
        const int row = tid >> 2, q = tid & 3;
        const int n = n0 + row;
        const float4* xp = (const float4*)(xs + (size_t)n * 128 + q * 32);
        const int sbase = row * 128;
#pragma unroll
        for (int i = 0; i < 4; ++i) {
            float4 a = make_float4(0.f, 0.f, 0.f, 0.f), c = a;
            if (n < N_NODES) { a = xp[2 * i]; c = xp[2 * i + 1]; }
            float vv[8] = {a.x, a.y, a.z, a.w, c.x, c.y, c.z, c.w};
            uint4 uh, ul;
            unsigned* ph = (unsigned*)&uh;
            unsigned* pl = (unsigned*)&ul;
#pragma unroll
            for (int j = 0; j < 4; ++j) {
                u16 h0 = f2bf(vv[2 * j]), h1 = f2bf(vv[2 * j + 1]);
                ph[j] = (unsigned)h0 | ((unsigned)h1 << 16);
                u16 l0 = f2bf(vv[2 * j] - bf2f(h0));
                u16 l1 = f2bf(vv[2 * j + 1] - bf2f(h1));
                pl[j] = (unsigned)l0 | ((unsigned)l1 << 16);
            }
            int ch = (q * 4 + i) ^ (row & 15);
            *(uint4*)&xhS[sbase + ch * 8] = uh;
            *(uint4*)&xlS[sbase + ch * 8] = ul;
        }
    }
    __syncthreads();

    const int lane = tid & 63, w = tid >> 6;
    const int l15 = lane & 15, l4 = lane >> 4;
    f32x4 acc[4][2];
    const f32x4 z4 = {0.f, 0.f, 0.f, 0.f};
#pragma unroll
    for (int m = 0; m < 4; ++m)
#pragma unroll
        for (int n = 0; n < 2; ++n) acc[m][n] = z4;

#pragma unroll
    for (int ks = 0; ks < 4; ++ks) {
        const int ch = (ks * 4 + l4) ^ l15;
        bf16x8 ah[4], al[4];
#pragma unroll
        for (int m = 0; m < 4; ++m) {
            ah[m] = *(const bf16x8*)&xhS[(m * 16 + l15) * 128 + ch * 8];
            al[m] = *(const bf16x8*)&xlS[(m * 16 + l15) * 128 + ch * 8];
        }
        bf16x8 bh[2], bl[2];
#pragma unroll
        for (int n = 0; n < 2; ++n) {
            size_t wo = (size_t)(w * 32 + n * 16 + l15) * 128 + ks * 32 + l4 * 8;
            bh[n] = *(const bf16x8*)(WTh + wo);
            bl[n] = *(const bf16x8*)(WTl + wo);
        }
#pragma unroll
        for (int m = 0; m < 4; ++m)
#pragma unroll
            for (int n = 0; n < 2; ++n) {
                acc[m][n] = mfma16(ah[m], bh[n], acc[m][n]);
                acc[m][n] = mfma16(ah[m], bl[n], acc[m][n]);
                acc[m][n] = mfma16(al[m], bh[n], acc[m][n]);
            }
    }

    // C/D: col = lane&15, row = (lane>>4)*4 + reg
#pragma unroll
    for (int n = 0; n < 2; ++n) {
        int c = w * 32 + n * 16 + l15;
        float bb = b[c];
#pragma unroll
        for (int m = 0; m < 4; ++m)
#pragma unroll
            for (int j = 0; j < 4; ++j) {
                int r = m * 16 + l4 * 4 + j;
                int ng = n0 + r;
                if (ng < N_NODES)
                    O[(size_t)ng * 128 + c] = f2bf(acc[m][n][j] + bb);
            }
    }
}

// ---------------------------------------------------------------------------
// Fused attention: one wave per node. Phase A: logits over all CSR edges
// (ts<=t), cached in LDS (logit + src), running per-head max/min. Phase B:
// exp sums from cache. Phase C: V accumulate in registers, single hat write.
// Slow-path recompute covers degree > CAP (practically never).
// ---------------------------------------------------------------------------
__global__ __launch_bounds__(256) void attn_fused_kernel(
    const u16* __restrict__ Qall, const u16* __restrict__ Kall,
    const u16* __restrict__ Vall,
    const int* __restrict__ offs, const int* __restrict__ srcbuf,
    float* __restrict__ hat_c, float* __restrict__ hat_s, int t_tar)
{
    __shared__ float logitS[4][CAP][NH];
    __shared__ int   srcS[4][CAP];
    const int lane = threadIdx.x & 63;
    const int wave = threadIdx.x >> 6;
    const int node = blockIdx.x * 4 + wave;
    if (node >= N_NODES) return;

    const size_t NHID = (size_t)N_NODES * HID;
    const u16* __restrict__ Qt = Qall + (size_t)t_tar * NHID;
    const int h  = lane & 7;      // phase A/B: head
    const int j8 = lane >> 3;     // phase A/B: edge slot

    float (*lg)[NH] = logitS[wave];
    int* sx = srcS[wave];

    // Q fragment for head h (32B)
    uint4 q0, q1;
    {
        const uint4* qp = (const uint4*)(Qt + (size_t)node * HID + h * DK);
        q0 = qp[0]; q1 = qp[1];
    }

    // ---- Phase A: logits + max/min + LDS cache ----
    float mx = -1e30f, mn = 1e30f;
    int base = 0;
    for (int ts = 0; ts <= t_tar; ++ts) {
        const int beg = offs[ts * (N_NODES + 1) + node];
        const int end = offs[ts * (N_NODES + 1) + node + 1];
        const u16* __restrict__ K = Kall + (size_t)ts * NHID;
        const int* __restrict__ sb = srcbuf + (size_t)ts * E_PER_T;
        for (int j = beg + j8; j < end; j += 8) {
            int idx = base + (j - beg);
            int src = sb[j];
            const uint4* kp = (const uint4*)(K + (size_t)src * HID + h * DK);
            uint4 k0 = kp[0], k1 = kp[1];
            float s = 0.f;
            const unsigned* pa = (const unsigned*)&q0;
            const unsigned* pb = (const unsigned*)&k0;
#pragma unroll
            for (int i = 0; i < 4; ++i)
                s += __uint_as_float(pa[i] << 16) * __uint_as_float(pb[i] << 16)
                   + __uint_as_float(pa[i] & 0xffff0000u) * __uint_as_float(pb[i] & 0xffff0000u);
            pa = (const unsigned*)&q1; pb = (const unsigned*)&k1;
#pragma unroll
            for (int i = 0; i < 4; ++i)
                s += __uint_as_float(pa[i] << 16) * __uint_as_float(pb[i] << 16)
                   + __uint_as_float(pa[i] & 0xffff0000u) * __uint_as_float(pb[i] & 0xffff0000u);
            s *= 0.25f;  // / sqrt(16)
            mx = fmaxf(mx, s);
            mn = fminf(mn, s);
            if (idx < CAP) { lg[idx][h] = s; if (h == 0) sx[idx] = src; }
        }
        base += end - beg;
    }
    const int dtot = base;
    if (dtot == 0) {  // no edges: hat rows are zero
        size_t bidx = (size_t)node * HID + 2 * lane;
        *(float2*)(hat_c + bidx) = make_float2(0.f, 0.f);
        *(float2*)(hat_s + bidx) = make_float2(0.f, 0.f);
        return;
    }
#pragma unroll
    for (int o = 8; o < 64; o <<= 1) {
        mx = fmaxf(mx, __shfl_xor(mx, o));
        mn = fminf(mn, __shfl_xor(mn, o));
    }

    // ---- Phase B: exp sums ----
    float sc = 0.f, ss = 0.f;
    {
        const int nfast = dtot < CAP ? dtot : CAP;
        for (int idx = j8; idx < nfast; idx += 8) {
            float a = lg[idx][h];
            sc += __expf(a - mx);
            ss += __expf(mn - a);
        }
        if (dtot > CAP) {  // slow path: re-walk CSR for idx >= CAP
            int b2 = 0;
            for (int ts = 0; ts <= t_tar; ++ts) {
                const int beg = offs[ts * (N_NODES + 1) + node];
                const int end = offs[ts * (N_NODES + 1) + node + 1];
                const u16* K = Kall + (size_t)ts * NHID;
                const int* sb = srcbuf + (size_t)ts * E_PER_T;
                for (int j = beg + j8; j < end; j += 8) {
                    int idx = b2 + (j - beg);
                    if (idx >= CAP) {
                        int src = sb[j];
                        const uint4* kp = (const uint4*)(K + (size_t)src * HID + h * DK);
                        uint4 k0 = kp[0], k1 = kp[1];
                        float s = 0.f;
                        const unsigned* pa = (const unsigned*)&q0;
                        const unsigned* pb = (const unsigned*)&k0;
#pragma unroll
                        for (int i = 0; i < 4; ++i)
                            s += __uint_as_float(pa[i] << 16) * __uint_as_float(pb[i] << 16)
                               + __uint_as_float(pa[i] & 0xffff0000u) * __uint_as_float(pb[i] & 0xffff0000u);
                        pa = (const unsigned*)&q1; pb = (const unsigned*)&k1;
#pragma unroll
                        for (int i = 0; i < 4; ++i)
                            s += __uint_as_float(pa[i] << 16) * __uint_as_float(pb[i] << 16)
                               + __uint_as_float(pa[i] & 0xffff0000u) * __uint_as_float(pb[i] & 0xffff0000u);
                        s *= 0.25f;
                        sc += __expf(s - mx);
                        ss += __expf(mn - s);
                    }
                }
                b2 += end - beg;
            }
        }
    }
#pragma unroll
    for (int o = 8; o < 64; o <<= 1) {
        sc += __shfl_xor(sc, o);
        ss += __shfl_xor(ss, o);
    }

    // ---- Phase C: V accumulate (lane owns dims 2l,2l+1; head = lane>>3) ----
    const int h2 = lane >> 3;
    const float mc   = __shfl(mx, h2);
    const float mnn  = __shfl(mn, h2);
    const float isc  = 1.f / (__shfl(sc, h2) + 1e-16f);
    const float iss  = 1.f / (__shfl(ss, h2) + 1e-16f);

    float aC0 = 0.f, aC1 = 0.f, aS0 = 0.f, aS1 = 0.f;
    base = 0;
    for (int ts = 0; ts <= t_tar; ++ts) {
        const int beg = offs[ts * (N_NODES + 1) + node];
        const int end = offs[ts * (N_NODES + 1) + node + 1];
        const u16* __restrict__ V = Vall + (size_t)ts * NHID;
        const int* __restrict__ sb = srcbuf + (size_t)ts * E_PER_T;
        for (int j = beg; j < end; ++j) {
            int idx = base + (j - beg);
            float a; int src;
            if (idx < CAP) {
                a = lg[idx][h2];
                src = sx[idx];
            } else {  // recompute dot in per-dim layout
                src = sb[j];
                unsigned qd = *(const unsigned*)(Qt + (size_t)node * HID + 2 * lane);
                unsigned kd = *(const unsigned*)(Kall + (size_t)ts * NHID + (size_t)src * HID + 2 * lane);
                float p = __uint_as_float(qd << 16) * __uint_as_float(kd << 16)
                        + __uint_as_float(qd & 0xffff0000u) * __uint_as_float(kd & 0xffff0000u);
                p += __shfl_xor(p, 1);
                p += __shfl_xor(p, 2);
                p += __shfl_xor(p, 4);
                a = p * 0.25f;
            }
            float pc = __expf(a - mc) * isc;
            float ps = __expf(mnn - a) * iss;
            unsigned v2 = *(const unsigned*)(V + (size_t)src * HID + 2 * lane);
            float v0 = __uint_as_float(v2 << 16);
            float v1 = __uint_as_float(v2 & 0xffff0000u);
            aC0 += v0 * pc; aC1 += v1 * pc;
            aS0 += v0 * ps; aS1 += v1 * ps;
        }
        base += end - beg;
    }
    size_t bidx = (size_t)node * HID + 2 * lane;
    *(float2*)(hat_c + bidx) = make_float2(aC0, aC1);
    *(float2*)(hat_s + bidx) = make_float2(aS0, aS1);
}

// ---------------------------------------------------------------------------
// FFN via MFMA + direct output: both branches in one block (spurious first,
// held in 32 regs), then out0=c+s, out1=c, out2=s. No combine pass.
// ---------------------------------------------------------------------------
__global__ __launch_bounds__(256) void ffn_out_kernel(
    const float* __restrict__ hat_c, const float* __restrict__ hat_s,
    const float* __restrict__ x,
    const float* __restrict__ ln_s, const float* __restrict__ ln_b,
    const u16* __restrict__ W1T, const float* __restrict__ b1,
    const u16* __restrict__ W2T, const float* __restrict__ b2,
    float* __restrict__ out, int t_tar)
{
    __shared__ u16 hnS[64 * 128];    // 16 KB
    __shared__ u16 hidS[64 * 256];   // 32 KB
    const int n0 = blockIdx.x * 64;
    const int tid = threadIdx.x;
    const float* __restrict__ xt = x + (size_t)t_tar * N_NODES * 128;
    const size_t TS = (size_t)T_WIN * N_NODES * HID;
    const size_t outbase = (size_t)t_tar * N_NODES * HID;

    const int lane = tid & 63, w = tid >> 6;
    const int l15 = lane & 15, l4 = lane >> 4;
    const f32x4 z4 = {0.f, 0.f, 0.f, 0.f};

    float sres[32];  // spurious branch result (static unrolled indexing)

    for (int pass = 0; pass < 2; ++pass) {
        const int br = 1 - pass;  // pass0: spurious, pass1: causal
        const float* __restrict__ hat = br ? hat_s : hat_c;

        // ---- LayerNorm: 4 threads/row ----
        {
            const int row = tid >> 2, q = tid & 3;
            const int n = n0 + row;
            float v[32];
            float s = 0.f, s2 = 0.f;
            if (n < N_NODES) {
                const float4* hp = (const float4*)(hat + (size_t)n * 128 + q * 32);
                const float4* xp = (const float4*)(xt + (size_t)n * 128 + q * 32);
#pragma unroll
                for (int i = 0; i < 8; ++i) {
                    float4 a = hp[i];
                    if (br == 0) {
                        float4 bx = xp[i];
                        a.x += bx.x; a.y += bx.y; a.z += bx.z; a.w += bx.w;
                    }
                    v[4 * i] = a.x; v[4 * i + 1] = a.y;
                    v[4 * i + 2] = a.z; v[4 * i + 3] = a.w;
                    s  += a.x + a.y + a.z + a.w;
                    s2 += a.x * a.x + a.y * a.y + a.z * a.z + a.w * a.w;
                }
            } else {
#pragma unroll
                for (int i = 0; i < 32; ++i) v[i] = 0.f;
            }
            s  += __shfl_xor(s, 1);  s  += __shfl_xor(s, 2);
            s2 += __shfl_xor(s2, 1); s2 += __shfl_xor(s2, 2);
            float mu  = s * (1.f / 128.f);
            float var = s2 * (1.f / 128.f) - mu * mu;
            float rstd = rsqrtf(var + 1e-5f);
            const int sbase = row * 128;
#pragma unroll
            for (int i = 0; i < 4; ++i) {
                uint4 uh; unsigned* ph = (unsigned*)&uh;
#pragma unroll
                for (int j = 0; j < 4; ++j) {
                    int c0 = q * 32 + i * 8 + 2 * j;
                    float h0 = (v[i * 8 + 2 * j]     - mu) * rstd * ln_s[c0]     + ln_b[c0];
                    float h1 = (v[i * 8 + 2 * j + 1] - mu) * rstd * ln_s[c0 + 1] + ln_b[c0 + 1];
                    if (n >= N_NODES) { h0 = 0.f; h1 = 0.f; }
                    ph[j] = (unsigned)f2bf(h0) | ((unsigned)f2bf(h1) << 16);
                }
                int ch = (q * 4 + i) ^ (row & 15);
                *(uint4*)&hnS[sbase + ch * 8] = uh;
            }
        }
        __syncthreads();

        // ---- GEMM1: wave w owns cols w*64..w*64+63 ----
        {
            f32x4 a1[4][4];
#pragma unroll
            for (int m = 0; m < 4; ++m)
#pragma unroll
                for (int n = 0; n < 4; ++n) a1[m][n] = z4;

#pragma unroll
            for (int ks = 0; ks < 4; ++ks) {
                const int ch = (ks * 4 + l4) ^ l15;
                bf16x8 af[4];
#pragma unroll
                for (int m = 0; m < 4; ++m)
                    af[m] = *(const bf16x8*)&hnS[(m * 16 + l15) * 128 + ch * 8];
                bf16x8 bfr[4];
#pragma unroll
                for (int n = 0; n < 4; ++n)
                    bfr[n] = *(const bf16x8*)(W1T + (size_t)(w * 64 + n * 16 + l15) * 128
                                                  + ks * 32 + l4 * 8);
#pragma unroll
                for (int m = 0; m < 4; ++m)
#pragma unroll
                    for (int n = 0; n < 4; ++n)
                        a1[m][n] = mfma16(af[m], bfr[n], a1[m][n]);
            }
            // bias + exact GELU -> swizzled bf16 hid tile
#pragma unroll
            for (int n = 0; n < 4; ++n) {
                int c = w * 64 + n * 16 + l15;
                float bb = b1[c];
#pragma unroll
                for (int m = 0; m < 4; ++m)
#pragma unroll
                    for (int j = 0; j < 4; ++j) {
                        int r = m * 16 + l4 * 4 + j;
                        float zz = a1[m][n][j] + bb;
                        float g = 0.5f * zz * (1.f + erff(zz * 0.70710678118654752f));
                        hidS[r * 256 + (((c >> 3) ^ (r & 15)) * 8) + (c & 7)] = f2bf(g);
                    }
            }
        }
        __syncthreads();

        // ---- GEMM2: wave w owns cols w*32..w*32+31 ----
        {
            f32x4 a2[4][2];
#pragma unroll
            for (int m = 0; m < 4; ++m)
#pragma unroll
                for (int n = 0; n < 2; ++n) a2[m][n] = z4;

#pragma unroll
            for (int ks = 0; ks < 8; ++ks) {
                const int ch = (ks * 4 + l4) ^ l15;
                bf16x8 af[4];
#pragma unroll
                for (int m = 0; m < 4; ++m)
                    af[m] = *(const bf16x8*)&hidS[(m * 16 + l15) * 256 + ch * 8];
                bf16x8 bfr[2];
#pragma unroll
                for (int n = 0; n < 2; ++n)
                    bfr[n] = *(const bf16x8*)(W2T + (size_t)(w * 32 + n * 16 + l15) * 256
                                                  + ks * 32 + l4 * 8);
#pragma unroll
                for (int m = 0; m < 4; ++m)
#pragma unroll
                    for (int n = 0; n < 2; ++n)
                        a2[m][n] = mfma16(af[m], bfr[n], a2[m][n]);
            }
            // epilogue: val = h + r; pass0 holds, pass1 writes out0/1/2
            int cnt = 0;
#pragma unroll
            for (int n = 0; n < 2; ++n) {
                int c = w * 32 + n * 16 + l15;
                float bb = b2[c];
#pragma unroll
                for (int m = 0; m < 4; ++m)
#pragma unroll
                    for (int j = 0; j < 4; ++j, ++cnt) {
                        int r = m * 16 + l4 * 4 + j;
                        int ng = n0 + r;
                        float val = a2[m][n][j] + bb;
                        if (ng < N_NODES) {
                            size_t idx = (size_t)ng * 128 + c;
                            float hv = hat[idx];
                            if (br == 0) hv += xt[idx];
                            val += hv;
                            if (pass == 1) {
                                float sv = sres[cnt];
                                size_t o = outbase + idx;
                                out[o]          = val + sv;
                                out[TS + o]     = val;
                                out[2 * TS + o] = sv;
                            }
                        }
                        if (pass == 0) sres[cnt] = val;
                    }
            }
        }
        __syncthreads();
    }
}

extern "C" void kernel_launch(void* const* d_in, const int* in_sizes, int n_in,
                              void* d_out, int out_size, void* d_ws, size_t ws_size,
                              hipStream_t stream) {
    const float* x    = (const float*)d_in[0];
    const int*   ei   = (const int*)  d_in[1];
    const float* Wq   = (const float*)d_in[2];
    const float* bq   = (const float*)d_in[3];
    const float* Wk   = (const float*)d_in[4];
    const float* bk   = (const float*)d_in[5];
    const float* Wv   = (const float*)d_in[6];
    const float* bv   = (const float*)d_in[7];
    const float* ln_s = (const float*)d_in[8];
    const float* ln_b = (const float*)d_in[9];
    const float* W1   = (const float*)d_in[10];
    const float* b1   = (const float*)d_in[11];
    const float* W2   = (const float*)d_in[12];
    const float* b2   = (const float*)d_in[13];
    float* out = (float*)d_out;

    // ---- Workspace layout (~171 MB; observed ws ~920 MB) ----
    const size_t NHID = (size_t)N_NODES * HID;  // 6,400,000
    char* p = (char*)d_ws;
    auto alloc = [&p](size_t bytes) -> void* {
        void* r = (void*)p;
        p += (bytes + 255) & ~(size_t)255;
        return r;
    };
    float* hat_c = (float*)alloc(NHID * 4);
    float* hat_s = (float*)alloc(NHID * 4);
    int* offs    = (int*)alloc((size_t)T_WIN * (N_NODES + 1) * 4);
    int* cursor  = (int*)alloc((size_t)T_WIN * N_NODES * 4);
    int* srcbuf  = (int*)alloc((size_t)T_WIN * E_PER_T * 4);
    u16* WqTh = (u16*)alloc(128 * 128 * 2);
    u16* WqTl = (u16*)alloc(128 * 128 * 2);
    u16* WkTh = (u16*)alloc(128 * 128 * 2);
    u16* WkTl = (u16*)alloc(128 * 128 * 2);
    u16* WvTh = (u16*)alloc(128 * 128 * 2);
    u16* WvTl = (u16*)alloc(128 * 128 * 2);
    u16* W1T  = (u16*)alloc(128 * 256 * 2);
    u16* W2T  = (u16*)alloc(256 * 128 * 2);
    u16* Qall = (u16*)alloc(3 * NHID * 2);
    u16* Kall = (u16*)alloc(3 * NHID * 2);
    u16* Vall = (u16*)alloc(3 * NHID * 2);

    const int PROJ_BLOCKS = (N_NODES + 63) / 64;          // 782
    const int NODE_BLOCKS = (N_NODES + 3) / 4;            // 12500
    const int TN_BLOCKS   = (T_WIN * N_NODES + 255) / 256;
    const int TE_BLOCKS   = (T_WIN * E_PER_T + 255) / 256;

    // ---- weight prep ----
    wsplit_kernel<<<64, 256, 0, stream>>>(Wq, WqTh, WqTl, 128, 128);
    wsplit_kernel<<<64, 256, 0, stream>>>(Wk, WkTh, WkTl, 128, 128);
    wsplit_kernel<<<64, 256, 0, stream>>>(Wv, WvTh, WvTl, 128, 128);
    wt_kernel<<<128, 256, 0, stream>>>(W1, W1T, 128, 256);
    wt_kernel<<<128, 256, 0, stream>>>(W2, W2T, 256, 128);

    // ---- CSR build ----
    zero_counts_kernel<<<TN_BLOCKS, 256, 0, stream>>>(cursor);
    hist_kernel<<<TE_BLOCKS, 256, 0, stream>>>(ei, cursor);
    scan_kernel<<<T_WIN, 1024, 0, stream>>>(cursor, offs);
    copy_cursor_kernel<<<TN_BLOCKS, 256, 0, stream>>>(offs, cursor);
    fill_kernel<<<TE_BLOCKS, 256, 0, stream>>>(ei, cursor, srcbuf);

    // ---- all projections (Q/K/V x 3 ts) in one dispatch ----
    {
        dim3 pg(PROJ_BLOCKS, 9);
        project_all_kernel<<<pg, 256, 0, stream>>>(
            x, WqTh, WqTl, bq, WkTh, WkTl, bk, WvTh, WvTl, bv,
            Qall, Kall, Vall);
    }

    for (int t = 0; t < T_WIN; ++t) {
        attn_fused_kernel<<<NODE_BLOCKS, 256, 0, stream>>>(
            Qall, Kall, Vall, offs, srcbuf, hat_c, hat_s, t);
        ffn_out_kernel<<<PROJ_BLOCKS, 256, 0, stream>>>(
            hat_c, hat_s, x, ln_s, ln_b, W1T, b1, W2T, b2, out, t);
    }
}

// Round 3
// 1171.073 us; speedup vs baseline: 1.3982x; 1.3982x over previous
//
#include <hip/hip_runtime.h>
#include <math.h>

// Problem constants (from reference)
#define T_WIN   3
#define N_NODES 50000
#define HID     128
#define E_PER_T 100000
#define NH      8
#define DK      16
#define CAP     64   // per-node LDS logit cache (avg total degree ~6; slow path covers overflow)

// R7: R6's fused ffn_out regressed (391us x3, VGPR=256 from sres[] held across
// two serialized passes -> 9.8% occupancy, all pipes idle). Rebuilt: 32-node
// tile, branches run IN PARALLEL across waves (0-1 causal, 2-3 spurious),
// spurious result crosses via 16KB LDS overlay, one pass, no live arrays.

typedef unsigned short u16;
typedef __attribute__((ext_vector_type(8))) short bf16x8;   // 8 bf16 = 4 VGPR
typedef __attribute__((ext_vector_type(4))) float f32x4;

__device__ __forceinline__ u16 f2bf(float v) {              // RNE f32->bf16
    unsigned u = __float_as_uint(v);
    return (u16)((u + 0x7fffu + ((u >> 16) & 1u)) >> 16);
}
__device__ __forceinline__ float bf2f(u16 u) {
    return __uint_as_float(((unsigned)u) << 16);
}
__device__ __forceinline__ f32x4 mfma16(bf16x8 a, bf16x8 b, f32x4 c) {
    return __builtin_amdgcn_mfma_f32_16x16x32_bf16(a, b, c, 0, 0, 0);
}

// ---------------------------------------------------------------------------
// Weight prep: transposed bf16 copies; wsplit also emits lo residual for
// fp32-equivalent split-MFMA. dst layout [C][R] (K contiguous).
// ---------------------------------------------------------------------------
__global__ __launch_bounds__(256) void wsplit_kernel(
    const float* __restrict__ src, u16* __restrict__ hi, u16* __restrict__ lo,
    int R, int C)
{
    int i = blockIdx.x * 256 + threadIdx.x;
    if (i >= R * C) return;
    int r = i / C, c = i - r * C;
    float v = src[i];
    u16 h = f2bf(v);
    hi[c * R + r] = h;
    lo[c * R + r] = f2bf(v - bf2f(h));
}

__global__ __launch_bounds__(256) void wt_kernel(
    const float* __restrict__ src, u16* __restrict__ dst, int R, int C)
{
    int i = blockIdx.x * 256 + threadIdx.x;
    if (i >= R * C) return;
    int r = i / C, c = i - r * C;
    dst[c * R + r] = f2bf(src[i]);
}

// ---------------------------------------------------------------------------
// CSR build (once). srcbuf stores SOURCE node ids in CSR order.
// ---------------------------------------------------------------------------
__global__ __launch_bounds__(256) void zero_counts_kernel(int* cursor)
{
    int i = blockIdx.x * 256 + threadIdx.x;
    if (i < T_WIN * N_NODES) cursor[i] = 0;
}

__global__ __launch_bounds__(256) void hist_kernel(
    const int* __restrict__ ei, int* counts)
{
    int i = blockIdx.x * 256 + threadIdx.x;
    if (i >= T_WIN * E_PER_T) return;
    int ts = i / E_PER_T;
    int e  = i - ts * E_PER_T;
    int tar = ei[(ts * 2 + 1) * E_PER_T + e];
    atomicAdd(&counts[ts * N_NODES + tar], 1);
}

__global__ __launch_bounds__(1024) void scan_kernel(
    const int* __restrict__ counts, int* __restrict__ offs)
{
    __shared__ int buf[1024];
    __shared__ int carry;
    const int ts = blockIdx.x;
    const int tid = threadIdx.x;
    if (tid == 0) carry = 0;
    __syncthreads();
    for (int base = 0; base < N_NODES; base += 1024) {
        int i = base + tid;
        int v = (i < N_NODES) ? counts[ts * N_NODES + i] : 0;
        buf[tid] = v;
        __syncthreads();
        for (int o = 1; o < 1024; o <<= 1) {
            int t = (tid >= o) ? buf[tid - o] : 0;
            __syncthreads();
            buf[tid] += t;
            __syncthreads();
        }
        int incl = buf[tid];
        if (i < N_NODES) offs[ts * (N_NODES + 1) + i] = carry + incl - v;
        __syncthreads();
        if (tid == 1023) carry += incl;
        __syncthreads();
    }
    if (tid == 0) offs[ts * (N_NODES + 1) + N_NODES] = carry;
}

__global__ __launch_bounds__(256) void copy_cursor_kernel(
    const int* __restrict__ offs, int* cursor)
{
    int i = blockIdx.x * 256 + threadIdx.x;
    if (i >= T_WIN * N_NODES) return;
    int ts = i / N_NODES;
    int n  = i - ts * N_NODES;
    cursor[i] = offs[ts * (N_NODES + 1) + n];
}

__global__ __launch_bounds__(256) void fill_kernel(
    const int* __restrict__ ei, int* cursor, int* __restrict__ srcbuf)
{
    int i = blockIdx.x * 256 + threadIdx.x;
    if (i >= T_WIN * E_PER_T) return;
    int ts = i / E_PER_T;
    int e  = i - ts * E_PER_T;
    int src = ei[(ts * 2) * E_PER_T + e];
    int tar = ei[(ts * 2 + 1) * E_PER_T + e];
    int pos = atomicAdd(&cursor[ts * N_NODES + tar], 1);
    srcbuf[ts * E_PER_T + pos] = src;
}

// ---------------------------------------------------------------------------
// Split-bf16 MFMA projection, ALL 9 (mat x ts) in one dispatch.
// blockIdx.y: ts = y/3, mat = y%3 (0=Q,1=K,2=V).
// ---------------------------------------------------------------------------
__global__ __launch_bounds__(256) void project_all_kernel(
    const float* __restrict__ x,
    const u16* __restrict__ QTh, const u16* __restrict__ QTl, const float* __restrict__ bq,
    const u16* __restrict__ KTh, const u16* __restrict__ KTl, const float* __restrict__ bk,
    const u16* __restrict__ VTh, const u16* __restrict__ VTl, const float* __restrict__ bv,
    u16* __restrict__ Qall, u16* __restrict__ Kall, u16* __restrict__ Vall)
{
    const int p  = blockIdx.y;
    const int ts = p / 3, mat = p - ts * 3;
    const u16 *WTh, *WTl; const float* b; u16* O;
    if (mat == 0)      { WTh = QTh; WTl = QTl; b = bq; O = Qall; }
    else if (mat == 1) { WTh = KTh; WTl = KTl; b = bk; O = Kall; }
    else               { WTh = VTh; WTl = VTl; b = bv; O = Vall; }
    const size_t NHID = (size_t)N_NODES * HID;
    const float* __restrict__ xs = x + (size_t)ts * NHID;
    O += (size_t)ts * NHID;

    __shared__ u16 xhS[64 * 128];
    __shared__ u16 xlS[64 * 128];
    const int tid = threadIdx.x;
    const int n0 = blockIdx.x * 64;

    {   // stage: 4 threads/row, each covers 32 cols; hi/lo split, swizzled
        const int row = tid >> 2, q = tid & 3;
        const int n = n0 + row;
        const float4* xp = (const float4*)(xs + (size_t)n * 128 + q * 32);
        const int sbase = row * 128;
#pragma unroll
        for (int i = 0; i < 4; ++i) {
            float4 a = make_float4(0.f, 0.f, 0.f, 0.f), c = a;
            if (n < N_NODES) { a = xp[2 * i]; c = xp[2 * i + 1]; }
            float vv[8] = {a.x, a.y, a.z, a.w, c.x, c.y, c.z, c.w};
            uint4 uh, ul;
            unsigned* ph = (unsigned*)&uh;
            unsigned* pl = (unsigned*)&ul;
#pragma unroll
            for (int j = 0; j < 4; ++j) {
                u16 h0 = f2bf(vv[2 * j]), h1 = f2bf(vv[2 * j + 1]);
                ph[j] = (unsigned)h0 | ((unsigned)h1 << 16);
                u16 l0 = f2bf(vv[2 * j] - bf2f(h0));
                u16 l1 = f2bf(vv[2 * j + 1] - bf2f(h1));
                pl[j] = (unsigned)l0 | ((unsigned)l1 << 16);
            }
            int ch = (q * 4 + i) ^ (row & 15);
            *(uint4*)&xhS[sbase + ch * 8] = uh;
            *(uint4*)&xlS[sbase + ch * 8] = ul;
        }
    }
    __syncthreads();

    const int lane = tid & 63, w = tid >> 6;
    const int l15 = lane & 15, l4 = lane >> 4;
    f32x4 acc[4][2];
    const f32x4 z4 = {0.f, 0.f, 0.f, 0.f};
#pragma unroll
    for (int m = 0; m < 4; ++m)
#pragma unroll
        for (int n = 0; n < 2; ++n) acc[m][n] = z4;

#pragma unroll
    for (int ks = 0; ks < 4; ++ks) {
        const int ch = (ks * 4 + l4) ^ l15;
        bf16x8 ah[4], al[4];
#pragma unroll
        for (int m = 0; m < 4; ++m) {
            ah[m] = *(const bf16x8*)&xhS[(m * 16 + l15) * 128 + ch * 8];
            al[m] = *(const bf16x8*)&xlS[(m * 16 + l15) * 128 + ch * 8];
        }
        bf16x8 bh[2], bl[2];
#pragma unroll
        for (int n = 0; n < 2; ++n) {
            size_t wo = (size_t)(w * 32 + n * 16 + l15) * 128 + ks * 32 + l4 * 8;
            bh[n] = *(const bf16x8*)(WTh + wo);
            bl[n] = *(const bf16x8*)(WTl + wo);
        }
#pragma unroll
        for (int m = 0; m < 4; ++m)
#pragma unroll
            for (int n = 0; n < 2; ++n) {
                acc[m][n] = mfma16(ah[m], bh[n], acc[m][n]);
                acc[m][n] = mfma16(ah[m], bl[n], acc[m][n]);
                acc[m][n] = mfma16(al[m], bh[n], acc[m][n]);
            }
    }

    // C/D: col = lane&15, row = (lane>>4)*4 + reg
#pragma unroll
    for (int n = 0; n < 2; ++n) {
        int c = w * 32 + n * 16 + l15;
        float bb = b[c];
#pragma unroll
        for (int m = 0; m < 4; ++m)
#pragma unroll
            for (int j = 0; j < 4; ++j) {
                int r = m * 16 + l4 * 4 + j;
                int ng = n0 + r;
                if (ng < N_NODES)
                    O[(size_t)ng * 128 + c] = f2bf(acc[m][n][j] + bb);
            }
    }
}

// ---------------------------------------------------------------------------
// Fused attention: one wave per node. Phase A: logits over all CSR edges
// (ts<=t), cached in LDS (logit + src), running per-head max/min. Phase B:
// exp sums from cache. Phase C: V accumulate in registers, single hat write.
// ---------------------------------------------------------------------------
__global__ __launch_bounds__(256) void attn_fused_kernel(
    const u16* __restrict__ Qall, const u16* __restrict__ Kall,
    const u16* __restrict__ Vall,
    const int* __restrict__ offs, const int* __restrict__ srcbuf,
    float* __restrict__ hat_c, float* __restrict__ hat_s, int t_tar)
{
    __shared__ float logitS[4][CAP][NH];
    __shared__ int   srcS[4][CAP];
    const int lane = threadIdx.x & 63;
    const int wave = threadIdx.x >> 6;
    const int node = blockIdx.x * 4 + wave;
    if (node >= N_NODES) return;

    const size_t NHID = (size_t)N_NODES * HID;
    const u16* __restrict__ Qt = Qall + (size_t)t_tar * NHID;
    const int h  = lane & 7;      // phase A/B: head
    const int j8 = lane >> 3;     // phase A/B: edge slot

    float (*lg)[NH] = logitS[wave];
    int* sx = srcS[wave];

    uint4 q0, q1;
    {
        const uint4* qp = (const uint4*)(Qt + (size_t)node * HID + h * DK);
        q0 = qp[0]; q1 = qp[1];
    }

    // ---- Phase A: logits + max/min + LDS cache ----
    float mx = -1e30f, mn = 1e30f;
    int base = 0;
    for (int ts = 0; ts <= t_tar; ++ts) {
        const int beg = offs[ts * (N_NODES + 1) + node];
        const int end = offs[ts * (N_NODES + 1) + node + 1];
        const u16* __restrict__ K = Kall + (size_t)ts * NHID;
        const int* __restrict__ sb = srcbuf + (size_t)ts * E_PER_T;
        for (int j = beg + j8; j < end; j += 8) {
            int idx = base + (j - beg);
            int src = sb[j];
            const uint4* kp = (const uint4*)(K + (size_t)src * HID + h * DK);
            uint4 k0 = kp[0], k1 = kp[1];
            float s = 0.f;
            const unsigned* pa = (const unsigned*)&q0;
            const unsigned* pb = (const unsigned*)&k0;
#pragma unroll
            for (int i = 0; i < 4; ++i)
                s += __uint_as_float(pa[i] << 16) * __uint_as_float(pb[i] << 16)
                   + __uint_as_float(pa[i] & 0xffff0000u) * __uint_as_float(pb[i] & 0xffff0000u);
            pa = (const unsigned*)&q1; pb = (const unsigned*)&k1;
#pragma unroll
            for (int i = 0; i < 4; ++i)
                s += __uint_as_float(pa[i] << 16) * __uint_as_float(pb[i] << 16)
                   + __uint_as_float(pa[i] & 0xffff0000u) * __uint_as_float(pb[i] & 0xffff0000u);
            s *= 0.25f;  // / sqrt(16)
            mx = fmaxf(mx, s);
            mn = fminf(mn, s);
            if (idx < CAP) { lg[idx][h] = s; if (h == 0) sx[idx] = src; }
        }
        base += end - beg;
    }
    const int dtot = base;
    if (dtot == 0) {
        size_t bidx = (size_t)node * HID + 2 * lane;
        *(float2*)(hat_c + bidx) = make_float2(0.f, 0.f);
        *(float2*)(hat_s + bidx) = make_float2(0.f, 0.f);
        return;
    }
#pragma unroll
    for (int o = 8; o < 64; o <<= 1) {
        mx = fmaxf(mx, __shfl_xor(mx, o));
        mn = fminf(mn, __shfl_xor(mn, o));
    }

    // ---- Phase B: exp sums ----
    float sc = 0.f, ss = 0.f;
    {
        const int nfast = dtot < CAP ? dtot : CAP;
        for (int idx = j8; idx < nfast; idx += 8) {
            float a = lg[idx][h];
            sc += __expf(a - mx);
            ss += __expf(mn - a);
        }
        if (dtot > CAP) {
            int b2 = 0;
            for (int ts = 0; ts <= t_tar; ++ts) {
                const int beg = offs[ts * (N_NODES + 1) + node];
                const int end = offs[ts * (N_NODES + 1) + node + 1];
                const u16* K = Kall + (size_t)ts * NHID;
                const int* sb = srcbuf + (size_t)ts * E_PER_T;
                for (int j = beg + j8; j < end; j += 8) {
                    int idx = b2 + (j - beg);
                    if (idx >= CAP) {
                        int src = sb[j];
                        const uint4* kp = (const uint4*)(K + (size_t)src * HID + h * DK);
                        uint4 k0 = kp[0], k1 = kp[1];
                        float s = 0.f;
                        const unsigned* pa = (const unsigned*)&q0;
                        const unsigned* pb = (const unsigned*)&k0;
#pragma unroll
                        for (int i = 0; i < 4; ++i)
                            s += __uint_as_float(pa[i] << 16) * __uint_as_float(pb[i] << 16)
                               + __uint_as_float(pa[i] & 0xffff0000u) * __uint_as_float(pb[i] & 0xffff0000u);
                        pa = (const unsigned*)&q1; pb = (const unsigned*)&k1;
#pragma unroll
                        for (int i = 0; i < 4; ++i)
                            s += __uint_as_float(pa[i] << 16) * __uint_as_float(pb[i] << 16)
                               + __uint_as_float(pa[i] & 0xffff0000u) * __uint_as_float(pb[i] & 0xffff0000u);
                        s *= 0.25f;
                        sc += __expf(s - mx);
                        ss += __expf(mn - s);
                    }
                }
                b2 += end - beg;
            }
        }
    }
#pragma unroll
    for (int o = 8; o < 64; o <<= 1) {
        sc += __shfl_xor(sc, o);
        ss += __shfl_xor(ss, o);
    }

    // ---- Phase C: V accumulate (lane owns dims 2l,2l+1; head = lane>>3) ----
    const int h2 = lane >> 3;
    const float mc   = __shfl(mx, h2);
    const float mnn  = __shfl(mn, h2);
    const float isc  = 1.f / (__shfl(sc, h2) + 1e-16f);
    const float iss  = 1.f / (__shfl(ss, h2) + 1e-16f);

    float aC0 = 0.f, aC1 = 0.f, aS0 = 0.f, aS1 = 0.f;
    base = 0;
    for (int ts = 0; ts <= t_tar; ++ts) {
        const int beg = offs[ts * (N_NODES + 1) + node];
        const int end = offs[ts * (N_NODES + 1) + node + 1];
        const u16* __restrict__ V = Vall + (size_t)ts * NHID;
        const int* __restrict__ sb = srcbuf + (size_t)ts * E_PER_T;
        for (int j = beg; j < end; ++j) {
            int idx = base + (j - beg);
            float a; int src;
            if (idx < CAP) {
                a = lg[idx][h2];
                src = sx[idx];
            } else {
                src = sb[j];
                unsigned qd = *(const unsigned*)(Qt + (size_t)node * HID + 2 * lane);
                unsigned kd = *(const unsigned*)(Kall + (size_t)ts * NHID + (size_t)src * HID + 2 * lane);
                float p = __uint_as_float(qd << 16) * __uint_as_float(kd << 16)
                        + __uint_as_float(qd & 0xffff0000u) * __uint_as_float(kd & 0xffff0000u);
                p += __shfl_xor(p, 1);
                p += __shfl_xor(p, 2);
                p += __shfl_xor(p, 4);
                a = p * 0.25f;
            }
            float pc = __expf(a - mc) * isc;
            float ps = __expf(mnn - a) * iss;
            unsigned v2 = *(const unsigned*)(V + (size_t)src * HID + 2 * lane);
            float v0 = __uint_as_float(v2 << 16);
            float v1 = __uint_as_float(v2 & 0xffff0000u);
            aC0 += v0 * pc; aC1 += v1 * pc;
            aS0 += v0 * ps; aS1 += v1 * ps;
        }
        base += end - beg;
    }
    size_t bidx = (size_t)node * HID + 2 * lane;
    *(float2*)(hat_c + bidx) = make_float2(aC0, aC1);
    *(float2*)(hat_s + bidx) = make_float2(aS0, aS1);
}

// ---------------------------------------------------------------------------
// FFN via MFMA, BOTH branches in parallel: 32-node tile, 4 waves.
// waves 0-1: causal branch; waves 2-3: spurious branch (same tile).
// Per branch: LN (128 thr) -> GEMM1 [32,128]@[128,256] -> GELU ->
// GEMM2 [32,256]@[256,128]. Spurious result crosses to causal waves via
// 16KB LDS overlay (dead hn tile); direct out0/1/2 stores; no combine.
// ---------------------------------------------------------------------------
__global__ __launch_bounds__(256, 3) void ffn_out_kernel(
    const float* __restrict__ hat_c, const float* __restrict__ hat_s,
    const float* __restrict__ x,
    const float* __restrict__ ln_s, const float* __restrict__ ln_b,
    const u16* __restrict__ W1T, const float* __restrict__ b1,
    const u16* __restrict__ W2T, const float* __restrict__ b2,
    float* __restrict__ out, int t_tar)
{
    __shared__ u16 hnS[2][32 * 128];    // 16 KB  (also reused as sxS f32[32][128])
    __shared__ u16 hidS[2][32 * 256];   // 32 KB
    const int n0 = blockIdx.x * 32;
    const int tid = threadIdx.x;
    const float* __restrict__ xt = x + (size_t)t_tar * N_NODES * 128;
    const size_t TS = (size_t)T_WIN * N_NODES * HID;
    const size_t outbase = (size_t)t_tar * N_NODES * HID;

    const int lane = tid & 63;
    const int wave = tid >> 6;
    const int br   = wave >> 1;          // 0 causal, 1 spurious
    const int wv   = wave & 1;           // wave-within-branch
    const int l15 = lane & 15, l4 = lane >> 4;
    const f32x4 z4 = {0.f, 0.f, 0.f, 0.f};
    const float* __restrict__ hat = br ? hat_s : hat_c;

    // ---- LayerNorm: branch = tid>>7 (matches wave split), 4 threads/row ----
    {
        const int row = (tid & 127) >> 2, q = tid & 3;
        const int n = n0 + row;
        float v[32];
        float s = 0.f, s2 = 0.f;
        if (n < N_NODES) {
            const float4* hp = (const float4*)(hat + (size_t)n * 128 + q * 32);
            const float4* xp = (const float4*)(xt + (size_t)n * 128 + q * 32);
#pragma unroll
            for (int i = 0; i < 8; ++i) {
                float4 a = hp[i];
                if (br == 0) {
                    float4 bx = xp[i];
                    a.x += bx.x; a.y += bx.y; a.z += bx.z; a.w += bx.w;
                }
                v[4 * i] = a.x; v[4 * i + 1] = a.y;
                v[4 * i + 2] = a.z; v[4 * i + 3] = a.w;
                s  += a.x + a.y + a.z + a.w;
                s2 += a.x * a.x + a.y * a.y + a.z * a.z + a.w * a.w;
            }
        } else {
#pragma unroll
            for (int i = 0; i < 32; ++i) v[i] = 0.f;
        }
        s  += __shfl_xor(s, 1);  s  += __shfl_xor(s, 2);
        s2 += __shfl_xor(s2, 1); s2 += __shfl_xor(s2, 2);
        float mu  = s * (1.f / 128.f);
        float var = s2 * (1.f / 128.f) - mu * mu;
        float rstd = rsqrtf(var + 1e-5f);
        const int sbase = row * 128;
#pragma unroll
        for (int i = 0; i < 4; ++i) {
            uint4 uh; unsigned* ph = (unsigned*)&uh;
#pragma unroll
            for (int j = 0; j < 4; ++j) {
                int c0 = q * 32 + i * 8 + 2 * j;
                float h0 = (v[i * 8 + 2 * j]     - mu) * rstd * ln_s[c0]     + ln_b[c0];
                float h1 = (v[i * 8 + 2 * j + 1] - mu) * rstd * ln_s[c0 + 1] + ln_b[c0 + 1];
                if (n >= N_NODES) { h0 = 0.f; h1 = 0.f; }
                ph[j] = (unsigned)f2bf(h0) | ((unsigned)f2bf(h1) << 16);
            }
            int ch = (q * 4 + i) ^ (row & 15);
            *(uint4*)&hnS[br][sbase + ch * 8] = uh;
        }
    }
    __syncthreads();

    // ---- GEMM1: per branch M=32,N=256,K=128; wave wv owns cols wv*128.. ----
    {
        f32x4 a1[2][8];
#pragma unroll
        for (int m = 0; m < 2; ++m)
#pragma unroll
            for (int n = 0; n < 8; ++n) a1[m][n] = z4;

#pragma unroll
        for (int ks = 0; ks < 4; ++ks) {
            const int ch = (ks * 4 + l4) ^ l15;
            bf16x8 af[2];
#pragma unroll
            for (int m = 0; m < 2; ++m)
                af[m] = *(const bf16x8*)&hnS[br][(m * 16 + l15) * 128 + ch * 8];
#pragma unroll
            for (int n = 0; n < 8; ++n) {
                bf16x8 bfr = *(const bf16x8*)(W1T + (size_t)(wv * 128 + n * 16 + l15) * 128
                                                  + ks * 32 + l4 * 8);
#pragma unroll
                for (int m = 0; m < 2; ++m)
                    a1[m][n] = mfma16(af[m], bfr, a1[m][n]);
            }
        }
        // bias + exact GELU -> swizzled bf16 hid tile
#pragma unroll
        for (int n = 0; n < 8; ++n) {
            int c = wv * 128 + n * 16 + l15;
            float bb = b1[c];
#pragma unroll
            for (int m = 0; m < 2; ++m)
#pragma unroll
                for (int j = 0; j < 4; ++j) {
                    int r = m * 16 + l4 * 4 + j;
                    float zz = a1[m][n][j] + bb;
                    float g = 0.5f * zz * (1.f + erff(zz * 0.70710678118654752f));
                    hidS[br][r * 256 + (((c >> 3) ^ (r & 15)) * 8) + (c & 7)] = f2bf(g);
                }
        }
    }
    __syncthreads();

    // ---- GEMM2: per branch M=32,K=256,N=128; wave wv owns cols wv*64.. ----
    f32x4 a2[2][4];
#pragma unroll
    for (int m = 0; m < 2; ++m)
#pragma unroll
        for (int n = 0; n < 4; ++n) a2[m][n] = z4;

#pragma unroll
    for (int ks = 0; ks < 8; ++ks) {
        const int ch = (ks * 4 + l4) ^ l15;
        bf16x8 af[2];
#pragma unroll
        for (int m = 0; m < 2; ++m)
            af[m] = *(const bf16x8*)&hidS[br][(m * 16 + l15) * 256 + ch * 8];
#pragma unroll
        for (int n = 0; n < 4; ++n) {
            bf16x8 bfr = *(const bf16x8*)(W2T + (size_t)(wv * 64 + n * 16 + l15) * 256
                                              + ks * 32 + l4 * 8);
#pragma unroll
            for (int m = 0; m < 2; ++m)
                a2[m][n] = mfma16(af[m], bfr, a2[m][n]);
        }
    }

    // ---- epilogue: spurious stashes to LDS + writes out2; causal writes
    //      out0/out1 after sync. sxS overlays the dead hn tiles (16 KB). ----
    float* sxS = (float*)&hnS[0][0];
    if (br == 1) {
#pragma unroll
        for (int n = 0; n < 4; ++n) {
            int c = wv * 64 + n * 16 + l15;
            float bb = b2[c];
#pragma unroll
            for (int m = 0; m < 2; ++m)
#pragma unroll
                for (int j = 0; j < 4; ++j) {
                    int r = m * 16 + l4 * 4 + j;
                    int ng = n0 + r;
                    float val = a2[m][n][j] + bb;
                    if (ng < N_NODES) {
                        size_t idx = (size_t)ng * 128 + c;
                        val += hat_s[idx];
                        out[2 * TS + outbase + idx] = val;
                    }
                    sxS[r * 128 + c] = val;
                }
        }
    }
    __syncthreads();
    if (br == 0) {
#pragma unroll
        for (int n = 0; n < 4; ++n) {
            int c = wv * 64 + n * 16 + l15;
            float bb = b2[c];
#pragma unroll
            for (int m = 0; m < 2; ++m)
#pragma unroll
                for (int j = 0; j < 4; ++j) {
                    int r = m * 16 + l4 * 4 + j;
                    int ng = n0 + r;
                    if (ng < N_NODES) {
                        size_t idx = (size_t)ng * 128 + c;
                        float val = a2[m][n][j] + bb + hat_c[idx] + xt[idx];
                        float sv = sxS[r * 128 + c];
                        size_t o = outbase + idx;
                        out[o]      = val + sv;
                        out[TS + o] = val;
                    }
                }
        }
    }
}

extern "C" void kernel_launch(void* const* d_in, const int* in_sizes, int n_in,
                              void* d_out, int out_size, void* d_ws, size_t ws_size,
                              hipStream_t stream) {
    const float* x    = (const float*)d_in[0];
    const int*   ei   = (const int*)  d_in[1];
    const float* Wq   = (const float*)d_in[2];
    const float* bq   = (const float*)d_in[3];
    const float* Wk   = (const float*)d_in[4];
    const float* bk   = (const float*)d_in[5];
    const float* Wv   = (const float*)d_in[6];
    const float* bv   = (const float*)d_in[7];
    const float* ln_s = (const float*)d_in[8];
    const float* ln_b = (const float*)d_in[9];
    const float* W1   = (const float*)d_in[10];
    const float* b1   = (const float*)d_in[11];
    const float* W2   = (const float*)d_in[12];
    const float* b2   = (const float*)d_in[13];
    float* out = (float*)d_out;

    // ---- Workspace layout (~171 MB) ----
    const size_t NHID = (size_t)N_NODES * HID;  // 6,400,000
    char* p = (char*)d_ws;
    auto alloc = [&p](size_t bytes) -> void* {
        void* r = (void*)p;
        p += (bytes + 255) & ~(size_t)255;
        return r;
    };
    float* hat_c = (float*)alloc(NHID * 4);
    float* hat_s = (float*)alloc(NHID * 4);
    int* offs    = (int*)alloc((size_t)T_WIN * (N_NODES + 1) * 4);
    int* cursor  = (int*)alloc((size_t)T_WIN * N_NODES * 4);
    int* srcbuf  = (int*)alloc((size_t)T_WIN * E_PER_T * 4);
    u16* WqTh = (u16*)alloc(128 * 128 * 2);
    u16* WqTl = (u16*)alloc(128 * 128 * 2);
    u16* WkTh = (u16*)alloc(128 * 128 * 2);
    u16* WkTl = (u16*)alloc(128 * 128 * 2);
    u16* WvTh = (u16*)alloc(128 * 128 * 2);
    u16* WvTl = (u16*)alloc(128 * 128 * 2);
    u16* W1T  = (u16*)alloc(128 * 256 * 2);
    u16* W2T  = (u16*)alloc(256 * 128 * 2);
    u16* Qall = (u16*)alloc(3 * NHID * 2);
    u16* Kall = (u16*)alloc(3 * NHID * 2);
    u16* Vall = (u16*)alloc(3 * NHID * 2);

    const int PROJ_BLOCKS = (N_NODES + 63) / 64;          // 782
    const int FFN_BLOCKS  = (N_NODES + 31) / 32;          // 1563
    const int NODE_BLOCKS = (N_NODES + 3) / 4;            // 12500
    const int TN_BLOCKS   = (T_WIN * N_NODES + 255) / 256;
    const int TE_BLOCKS   = (T_WIN * E_PER_T + 255) / 256;

    // ---- weight prep ----
    wsplit_kernel<<<64, 256, 0, stream>>>(Wq, WqTh, WqTl, 128, 128);
    wsplit_kernel<<<64, 256, 0, stream>>>(Wk, WkTh, WkTl, 128, 128);
    wsplit_kernel<<<64, 256, 0, stream>>>(Wv, WvTh, WvTl, 128, 128);
    wt_kernel<<<128, 256, 0, stream>>>(W1, W1T, 128, 256);
    wt_kernel<<<128, 256, 0, stream>>>(W2, W2T, 256, 128);

    // ---- CSR build ----
    zero_counts_kernel<<<TN_BLOCKS, 256, 0, stream>>>(cursor);
    hist_kernel<<<TE_BLOCKS, 256, 0, stream>>>(ei, cursor);
    scan_kernel<<<T_WIN, 1024, 0, stream>>>(cursor, offs);
    copy_cursor_kernel<<<TN_BLOCKS, 256, 0, stream>>>(offs, cursor);
    fill_kernel<<<TE_BLOCKS, 256, 0, stream>>>(ei, cursor, srcbuf);

    // ---- all projections (Q/K/V x 3 ts) in one dispatch ----
    {
        dim3 pg(PROJ_BLOCKS, 9);
        project_all_kernel<<<pg, 256, 0, stream>>>(
            x, WqTh, WqTl, bq, WkTh, WkTl, bk, WvTh, WvTl, bv,
            Qall, Kall, Vall);
    }

    for (int t = 0; t < T_WIN; ++t) {
        attn_fused_kernel<<<NODE_BLOCKS, 256, 0, stream>>>(
            Qall, Kall, Vall, offs, srcbuf, hat_c, hat_s, t);
        ffn_out_kernel<<<FFN_BLOCKS, 256, 0, stream>>>(
            hat_c, hat_s, x, ln_s, ln_b, W1T, b1, W2T, b2, out, t);
    }
}

// Round 4
// 1118.587 us; speedup vs baseline: 1.4638x; 1.0469x over previous
//
#include <hip/hip_runtime.h>
#include <math.h>

// Problem constants (from reference)
#define T_WIN   3
#define N_NODES 50000
#define HID     128
#define E_PER_T 100000
#define NH      8
#define DK      16
#define CAP     64   // per-node LDS logit cache (avg total degree ~6; slow path covers overflow)

// R8: ffn still latency-bound (207us x3: MfmaUtil 2.5%, VALU 15%, HBM 13%,
// occ 27.7% capped by 48KB LDS = 3 blocks/CU; 3 serialized dispatches).
// Fix: (1) chunked GEMM1->GEMM2 fusion drops hidS => LDS 32KB = 5 blocks/CU;
// (2) all t merged into ONE attn dispatch + ONE ffn dispatch (t independent);
// (3) weight prep merged to 1 dispatch. Arithmetic order bit-identical.

typedef unsigned short u16;
typedef __attribute__((ext_vector_type(8))) short bf16x8;   // 8 bf16 = 4 VGPR
typedef __attribute__((ext_vector_type(4))) float f32x4;

__device__ __forceinline__ u16 f2bf(float v) {              // RNE f32->bf16
    unsigned u = __float_as_uint(v);
    return (u16)((u + 0x7fffu + ((u >> 16) & 1u)) >> 16);
}
__device__ __forceinline__ float bf2f(u16 u) {
    return __uint_as_float(((unsigned)u) << 16);
}
__device__ __forceinline__ f32x4 mfma16(bf16x8 a, bf16x8 b, f32x4 c) {
    return __builtin_amdgcn_mfma_f32_16x16x32_bf16(a, b, c, 0, 0, 0);
}

// ---------------------------------------------------------------------------
// Weight prep, ONE dispatch. y=0..2: hi/lo split of Wq/Wk/Wv (128x128);
// y=3: W1 (128x256) bf16; y=4: W2 (256x128) bf16. dst layout [C][R].
// ---------------------------------------------------------------------------
__global__ __launch_bounds__(256) void wprep_kernel(
    const float* __restrict__ Wq, const float* __restrict__ Wk,
    const float* __restrict__ Wv, const float* __restrict__ W1,
    const float* __restrict__ W2,
    u16* __restrict__ WqTh, u16* __restrict__ WqTl,
    u16* __restrict__ WkTh, u16* __restrict__ WkTl,
    u16* __restrict__ WvTh, u16* __restrict__ WvTl,
    u16* __restrict__ W1T, u16* __restrict__ W2T)
{
    const int y = blockIdx.y;
    int i = blockIdx.x * 256 + threadIdx.x;
    if (y < 3) {
        if (i >= 128 * 128) return;
        const float* src = (y == 0) ? Wq : (y == 1) ? Wk : Wv;
        u16* hi = (y == 0) ? WqTh : (y == 1) ? WkTh : WvTh;
        u16* lo = (y == 0) ? WqTl : (y == 1) ? WkTl : WvTl;
        int r = i >> 7, c = i & 127;
        float v = src[i];
        u16 h = f2bf(v);
        hi[c * 128 + r] = h;
        lo[c * 128 + r] = f2bf(v - bf2f(h));
    } else if (y == 3) {
        if (i >= 128 * 256) return;
        int r = i >> 8, c = i & 255;
        W1T[c * 128 + r] = f2bf(W1[i]);
    } else {
        if (i >= 256 * 128) return;
        int r = i >> 7, c = i & 127;
        W2T[c * 256 + r] = f2bf(W2[i]);
    }
}

// ---------------------------------------------------------------------------
// CSR build (once). srcbuf stores SOURCE node ids in CSR order.
// ---------------------------------------------------------------------------
__global__ __launch_bounds__(256) void zero_counts_kernel(int* cursor)
{
    int i = blockIdx.x * 256 + threadIdx.x;
    if (i < T_WIN * N_NODES) cursor[i] = 0;
}

__global__ __launch_bounds__(256) void hist_kernel(
    const int* __restrict__ ei, int* counts)
{
    int i = blockIdx.x * 256 + threadIdx.x;
    if (i >= T_WIN * E_PER_T) return;
    int ts = i / E_PER_T;
    int e  = i - ts * E_PER_T;
    int tar = ei[(ts * 2 + 1) * E_PER_T + e];
    atomicAdd(&counts[ts * N_NODES + tar], 1);
}

__global__ __launch_bounds__(1024) void scan_kernel(
    const int* __restrict__ counts, int* __restrict__ offs)
{
    __shared__ int buf[1024];
    __shared__ int carry;
    const int ts = blockIdx.x;
    const int tid = threadIdx.x;
    if (tid == 0) carry = 0;
    __syncthreads();
    for (int base = 0; base < N_NODES; base += 1024) {
        int i = base + tid;
        int v = (i < N_NODES) ? counts[ts * N_NODES + i] : 0;
        buf[tid] = v;
        __syncthreads();
        for (int o = 1; o < 1024; o <<= 1) {
            int t = (tid >= o) ? buf[tid - o] : 0;
            __syncthreads();
            buf[tid] += t;
            __syncthreads();
        }
        int incl = buf[tid];
        if (i < N_NODES) offs[ts * (N_NODES + 1) + i] = carry + incl - v;
        __syncthreads();
        if (tid == 1023) carry += incl;
        __syncthreads();
    }
    if (tid == 0) offs[ts * (N_NODES + 1) + N_NODES] = carry;
}

__global__ __launch_bounds__(256) void copy_cursor_kernel(
    const int* __restrict__ offs, int* cursor)
{
    int i = blockIdx.x * 256 + threadIdx.x;
    if (i >= T_WIN * N_NODES) return;
    int ts = i / N_NODES;
    int n  = i - ts * N_NODES;
    cursor[i] = offs[ts * (N_NODES + 1) + n];
}

__global__ __launch_bounds__(256) void fill_kernel(
    const int* __restrict__ ei, int* cursor, int* __restrict__ srcbuf)
{
    int i = blockIdx.x * 256 + threadIdx.x;
    if (i >= T_WIN * E_PER_T) return;
    int ts = i / E_PER_T;
    int e  = i - ts * E_PER_T;
    int src = ei[(ts * 2) * E_PER_T + e];
    int tar = ei[(ts * 2 + 1) * E_PER_T + e];
    int pos = atomicAdd(&cursor[ts * N_NODES + tar], 1);
    srcbuf[ts * E_PER_T + pos] = src;
}

// ---------------------------------------------------------------------------
// Split-bf16 MFMA projection, ALL 9 (mat x ts) in one dispatch.
// blockIdx.y: ts = y/3, mat = y%3 (0=Q,1=K,2=V).
// ---------------------------------------------------------------------------
__global__ __launch_bounds__(256) void project_all_kernel(
    const float* __restrict__ x,
    const u16* __restrict__ QTh, const u16* __restrict__ QTl, const float* __restrict__ bq,
    const u16* __restrict__ KTh, const u16* __restrict__ KTl, const float* __restrict__ bk,
    const u16* __restrict__ VTh, const u16* __restrict__ VTl, const float* __restrict__ bv,
    u16* __restrict__ Qall, u16* __restrict__ Kall, u16* __restrict__ Vall)
{
    const int p  = blockIdx.y;
    const int ts = p / 3, mat = p - ts * 3;
    const u16 *WTh, *WTl; const float* b; u16* O;
    if (mat == 0)      { WTh = QTh; WTl = QTl; b = bq; O = Qall; }
    else if (mat == 1) { WTh = KTh; WTl = KTl; b = bk; O = Kall; }
    else               { WTh = VTh; WTl = VTl; b = bv; O = Vall; }
    const size_t NHID = (size_t)N_NODES * HID;
    const float* __restrict__ xs = x + (size_t)ts * NHID;
    O += (size_t)ts * NHID;

    __shared__ u16 xhS[64 * 128];
    __shared__ u16 xlS[64 * 128];
    const int tid = threadIdx.x;
    const int n0 = blockIdx.x * 64;

    {   // stage: 4 threads/row, each covers 32 cols; hi/lo split, swizzled
        const int row = tid >> 2, q = tid & 3;
        const int n = n0 + row;
        const float4* xp = (const float4*)(xs + (size_t)n * 128 + q * 32);
        const int sbase = row * 128;
#pragma unroll
        for (int i = 0; i < 4; ++i) {
            float4 a = make_float4(0.f, 0.f, 0.f, 0.f), c = a;
            if (n < N_NODES) { a = xp[2 * i]; c = xp[2 * i + 1]; }
            float vv[8] = {a.x, a.y, a.z, a.w, c.x, c.y, c.z, c.w};
            uint4 uh, ul;
            unsigned* ph = (unsigned*)&uh;
            unsigned* pl = (unsigned*)&ul;
#pragma unroll
            for (int j = 0; j < 4; ++j) {
                u16 h0 = f2bf(vv[2 * j]), h1 = f2bf(vv[2 * j + 1]);
                ph[j] = (unsigned)h0 | ((unsigned)h1 << 16);
                u16 l0 = f2bf(vv[2 * j] - bf2f(h0));
                u16 l1 = f2bf(vv[2 * j + 1] - bf2f(h1));
                pl[j] = (unsigned)l0 | ((unsigned)l1 << 16);
            }
            int ch = (q * 4 + i) ^ (row & 15);
            *(uint4*)&xhS[sbase + ch * 8] = uh;
            *(uint4*)&xlS[sbase + ch * 8] = ul;
        }
    }
    __syncthreads();

    const int lane = tid & 63, w = tid >> 6;
    const int l15 = lane & 15, l4 = lane >> 4;
    f32x4 acc[4][2];
    const f32x4 z4 = {0.f, 0.f, 0.f, 0.f};
#pragma unroll
    for (int m = 0; m < 4; ++m)
#pragma unroll
        for (int n = 0; n < 2; ++n) acc[m][n] = z4;

#pragma unroll
    for (int ks = 0; ks < 4; ++ks) {
        const int ch = (ks * 4 + l4) ^ l15;
        bf16x8 ah[4], al[4];
#pragma unroll
        for (int m = 0; m < 4; ++m) {
            ah[m] = *(const bf16x8*)&xhS[(m * 16 + l15) * 128 + ch * 8];
            al[m] = *(const bf16x8*)&xlS[(m * 16 + l15) * 128 + ch * 8];
        }
        bf16x8 bh[2], bl[2];
#pragma unroll
        for (int n = 0; n < 2; ++n) {
            size_t wo = (size_t)(w * 32 + n * 16 + l15) * 128 + ks * 32 + l4 * 8;
            bh[n] = *(const bf16x8*)(WTh + wo);
            bl[n] = *(const bf16x8*)(WTl + wo);
        }
#pragma unroll
        for (int m = 0; m < 4; ++m)
#pragma unroll
            for (int n = 0; n < 2; ++n) {
                acc[m][n] = mfma16(ah[m], bh[n], acc[m][n]);
                acc[m][n] = mfma16(ah[m], bl[n], acc[m][n]);
                acc[m][n] = mfma16(al[m], bh[n], acc[m][n]);
            }
    }

    // C/D: col = lane&15, row = (lane>>4)*4 + reg
#pragma unroll
    for (int n = 0; n < 2; ++n) {
        int c = w * 32 + n * 16 + l15;
        float bb = b[c];
#pragma unroll
        for (int m = 0; m < 4; ++m)
#pragma unroll
            for (int j = 0; j < 4; ++j) {
                int r = m * 16 + l4 * 4 + j;
                int ng = n0 + r;
                if (ng < N_NODES)
                    O[(size_t)ng * 128 + c] = f2bf(acc[m][n][j] + bb);
            }
    }
}

// ---------------------------------------------------------------------------
// Fused attention, ALL t in one dispatch (blockIdx.y = t_tar).
// One wave per node. Phase A: logits (LDS cache) + max/min; Phase B: exp
// sums; Phase C: V accumulate in registers, single hat write.
// ---------------------------------------------------------------------------
__global__ __launch_bounds__(256) void attn_fused_kernel(
    const u16* __restrict__ Qall, const u16* __restrict__ Kall,
    const u16* __restrict__ Vall,
    const int* __restrict__ offs, const int* __restrict__ srcbuf,
    float* __restrict__ hat_c_all, float* __restrict__ hat_s_all)
{
    __shared__ float logitS[4][CAP][NH];
    __shared__ int   srcS[4][CAP];
    const int t_tar = blockIdx.y;
    const int lane = threadIdx.x & 63;
    const int wave = threadIdx.x >> 6;
    const int node = blockIdx.x * 4 + wave;
    if (node >= N_NODES) return;

    const size_t NHID = (size_t)N_NODES * HID;
    float* __restrict__ hat_c = hat_c_all + (size_t)t_tar * NHID;
    float* __restrict__ hat_s = hat_s_all + (size_t)t_tar * NHID;
    const u16* __restrict__ Qt = Qall + (size_t)t_tar * NHID;
    const int h  = lane & 7;      // phase A/B: head
    const int j8 = lane >> 3;     // phase A/B: edge slot

    float (*lg)[NH] = logitS[wave];
    int* sx = srcS[wave];

    uint4 q0, q1;
    {
        const uint4* qp = (const uint4*)(Qt + (size_t)node * HID + h * DK);
        q0 = qp[0]; q1 = qp[1];
    }

    // ---- Phase A: logits + max/min + LDS cache ----
    float mx = -1e30f, mn = 1e30f;
    int base = 0;
    for (int ts = 0; ts <= t_tar; ++ts) {
        const int beg = offs[ts * (N_NODES + 1) + node];
        const int end = offs[ts * (N_NODES + 1) + node + 1];
        const u16* __restrict__ K = Kall + (size_t)ts * NHID;
        const int* __restrict__ sb = srcbuf + (size_t)ts * E_PER_T;
        for (int j = beg + j8; j < end; j += 8) {
            int idx = base + (j - beg);
            int src = sb[j];
            const uint4* kp = (const uint4*)(K + (size_t)src * HID + h * DK);
            uint4 k0 = kp[0], k1 = kp[1];
            float s = 0.f;
            const unsigned* pa = (const unsigned*)&q0;
            const unsigned* pb = (const unsigned*)&k0;
#pragma unroll
            for (int i = 0; i < 4; ++i)
                s += __uint_as_float(pa[i] << 16) * __uint_as_float(pb[i] << 16)
                   + __uint_as_float(pa[i] & 0xffff0000u) * __uint_as_float(pb[i] & 0xffff0000u);
            pa = (const unsigned*)&q1; pb = (const unsigned*)&k1;
#pragma unroll
            for (int i = 0; i < 4; ++i)
                s += __uint_as_float(pa[i] << 16) * __uint_as_float(pb[i] << 16)
                   + __uint_as_float(pa[i] & 0xffff0000u) * __uint_as_float(pb[i] & 0xffff0000u);
            s *= 0.25f;  // / sqrt(16)
            mx = fmaxf(mx, s);
            mn = fminf(mn, s);
            if (idx < CAP) { lg[idx][h] = s; if (h == 0) sx[idx] = src; }
        }
        base += end - beg;
    }
    const int dtot = base;
    if (dtot == 0) {
        size_t bidx = (size_t)node * HID + 2 * lane;
        *(float2*)(hat_c + bidx) = make_float2(0.f, 0.f);
        *(float2*)(hat_s + bidx) = make_float2(0.f, 0.f);
        return;
    }
#pragma unroll
    for (int o = 8; o < 64; o <<= 1) {
        mx = fmaxf(mx, __shfl_xor(mx, o));
        mn = fminf(mn, __shfl_xor(mn, o));
    }

    // ---- Phase B: exp sums ----
    float sc = 0.f, ss = 0.f;
    {
        const int nfast = dtot < CAP ? dtot : CAP;
        for (int idx = j8; idx < nfast; idx += 8) {
            float a = lg[idx][h];
            sc += __expf(a - mx);
            ss += __expf(mn - a);
        }
        if (dtot > CAP) {
            int b2 = 0;
            for (int ts = 0; ts <= t_tar; ++ts) {
                const int beg = offs[ts * (N_NODES + 1) + node];
                const int end = offs[ts * (N_NODES + 1) + node + 1];
                const u16* K = Kall + (size_t)ts * NHID;
                const int* sb = srcbuf + (size_t)ts * E_PER_T;
                for (int j = beg + j8; j < end; j += 8) {
                    int idx = b2 + (j - beg);
                    if (idx >= CAP) {
                        int src = sb[j];
                        const uint4* kp = (const uint4*)(K + (size_t)src * HID + h * DK);
                        uint4 k0 = kp[0], k1 = kp[1];
                        float s = 0.f;
                        const unsigned* pa = (const unsigned*)&q0;
                        const unsigned* pb = (const unsigned*)&k0;
#pragma unroll
                        for (int i = 0; i < 4; ++i)
                            s += __uint_as_float(pa[i] << 16) * __uint_as_float(pb[i] << 16)
                               + __uint_as_float(pa[i] & 0xffff0000u) * __uint_as_float(pb[i] & 0xffff0000u);
                        pa = (const unsigned*)&q1; pb = (const unsigned*)&k1;
#pragma unroll
                        for (int i = 0; i < 4; ++i)
                            s += __uint_as_float(pa[i] << 16) * __uint_as_float(pb[i] << 16)
                               + __uint_as_float(pa[i] & 0xffff0000u) * __uint_as_float(pb[i] & 0xffff0000u);
                        s *= 0.25f;
                        sc += __expf(s - mx);
                        ss += __expf(mn - s);
                    }
                }
                b2 += end - beg;
            }
        }
    }
#pragma unroll
    for (int o = 8; o < 64; o <<= 1) {
        sc += __shfl_xor(sc, o);
        ss += __shfl_xor(ss, o);
    }

    // ---- Phase C: V accumulate (lane owns dims 2l,2l+1; head = lane>>3) ----
    const int h2 = lane >> 3;
    const float mc   = __shfl(mx, h2);
    const float mnn  = __shfl(mn, h2);
    const float isc  = 1.f / (__shfl(sc, h2) + 1e-16f);
    const float iss  = 1.f / (__shfl(ss, h2) + 1e-16f);

    float aC0 = 0.f, aC1 = 0.f, aS0 = 0.f, aS1 = 0.f;
    base = 0;
    for (int ts = 0; ts <= t_tar; ++ts) {
        const int beg = offs[ts * (N_NODES + 1) + node];
        const int end = offs[ts * (N_NODES + 1) + node + 1];
        const u16* __restrict__ V = Vall + (size_t)ts * NHID;
        const int* __restrict__ sb = srcbuf + (size_t)ts * E_PER_T;
        for (int j = beg; j < end; ++j) {
            int idx = base + (j - beg);
            float a; int src;
            if (idx < CAP) {
                a = lg[idx][h2];
                src = sx[idx];
            } else {
                src = sb[j];
                unsigned qd = *(const unsigned*)(Qt + (size_t)node * HID + 2 * lane);
                unsigned kd = *(const unsigned*)(Kall + (size_t)ts * NHID + (size_t)src * HID + 2 * lane);
                float p = __uint_as_float(qd << 16) * __uint_as_float(kd << 16)
                        + __uint_as_float(qd & 0xffff0000u) * __uint_as_float(kd & 0xffff0000u);
                p += __shfl_xor(p, 1);
                p += __shfl_xor(p, 2);
                p += __shfl_xor(p, 4);
                a = p * 0.25f;
            }
            float pc = __expf(a - mc) * isc;
            float ps = __expf(mnn - a) * iss;
            unsigned v2 = *(const unsigned*)(V + (size_t)src * HID + 2 * lane);
            float v0 = __uint_as_float(v2 << 16);
            float v1 = __uint_as_float(v2 & 0xffff0000u);
            aC0 += v0 * pc; aC1 += v1 * pc;
            aS0 += v0 * ps; aS1 += v1 * ps;
        }
        base += end - beg;
    }
    size_t bidx = (size_t)node * HID + 2 * lane;
    *(float2*)(hat_c + bidx) = make_float2(aC0, aC1);
    *(float2*)(hat_s + bidx) = make_float2(aS0, aS1);
}

// ---------------------------------------------------------------------------
// FFN via MFMA, ALL t in one dispatch (blockIdx.y = t), both branches in
// parallel (waves 0-1 causal, 2-3 spurious), 32-node tile. GEMM1->GEMM2
// K-fused in 4 chunks of 64 hid cols through a double-buffered 16KB chS;
// LDS total 32KB => 5 blocks/CU. K-accumulation order identical to R7.
// ---------------------------------------------------------------------------
__global__ __launch_bounds__(256, 5) void ffn_out_kernel(
    const float* __restrict__ hat_c_all, const float* __restrict__ hat_s_all,
    const float* __restrict__ x,
    const float* __restrict__ ln_s, const float* __restrict__ ln_b,
    const u16* __restrict__ W1T, const float* __restrict__ b1,
    const u16* __restrict__ W2T, const float* __restrict__ b2,
    float* __restrict__ out)
{
    __shared__ u16 hnS[2][32 * 128];      // 16 KB (reused as sxS f32[32][128] at epilogue)
    __shared__ u16 chS[2][2][32 * 64];    // 16 KB: [buf][br][row*64+swz col]
    const int t_tar = blockIdx.y;
    const int n0 = blockIdx.x * 32;
    const int tid = threadIdx.x;
    const size_t NHID = (size_t)N_NODES * HID;
    const float* __restrict__ hat_c = hat_c_all + (size_t)t_tar * NHID;
    const float* __restrict__ hat_s = hat_s_all + (size_t)t_tar * NHID;
    const float* __restrict__ xt = x + (size_t)t_tar * NHID;
    const size_t TS = (size_t)T_WIN * N_NODES * HID;
    const size_t outbase = (size_t)t_tar * NHID;

    const int lane = tid & 63;
    const int wave = tid >> 6;
    const int br   = wave >> 1;          // 0 causal, 1 spurious
    const int wv   = wave & 1;           // wave-within-branch
    const int l15 = lane & 15, l4 = lane >> 4;
    const f32x4 z4 = {0.f, 0.f, 0.f, 0.f};
    const float* __restrict__ hat = br ? hat_s : hat_c;

    // ---- LayerNorm: branch = tid>>7 (matches wave split), 4 threads/row ----
    {
        const int row = (tid & 127) >> 2, q = tid & 3;
        const int n = n0 + row;
        float v[32];
        float s = 0.f, s2 = 0.f;
        if (n < N_NODES) {
            const float4* hp = (const float4*)(hat + (size_t)n * 128 + q * 32);
            const float4* xp = (const float4*)(xt + (size_t)n * 128 + q * 32);
#pragma unroll
            for (int i = 0; i < 8; ++i) {
                float4 a = hp[i];
                if (br == 0) {
                    float4 bx = xp[i];
                    a.x += bx.x; a.y += bx.y; a.z += bx.z; a.w += bx.w;
                }
                v[4 * i] = a.x; v[4 * i + 1] = a.y;
                v[4 * i + 2] = a.z; v[4 * i + 3] = a.w;
                s  += a.x + a.y + a.z + a.w;
                s2 += a.x * a.x + a.y * a.y + a.z * a.z + a.w * a.w;
            }
        } else {
#pragma unroll
            for (int i = 0; i < 32; ++i) v[i] = 0.f;
        }
        s  += __shfl_xor(s, 1);  s  += __shfl_xor(s, 2);
        s2 += __shfl_xor(s2, 1); s2 += __shfl_xor(s2, 2);
        float mu  = s * (1.f / 128.f);
        float var = s2 * (1.f / 128.f) - mu * mu;
        float rstd = rsqrtf(var + 1e-5f);
        const int sbase = row * 128;
#pragma unroll
        for (int i = 0; i < 4; ++i) {
            uint4 uh; unsigned* ph = (unsigned*)&uh;
#pragma unroll
            for (int j = 0; j < 4; ++j) {
                int c0 = q * 32 + i * 8 + 2 * j;
                float h0 = (v[i * 8 + 2 * j]     - mu) * rstd * ln_s[c0]     + ln_b[c0];
                float h1 = (v[i * 8 + 2 * j + 1] - mu) * rstd * ln_s[c0 + 1] + ln_b[c0 + 1];
                if (n >= N_NODES) { h0 = 0.f; h1 = 0.f; }
                ph[j] = (unsigned)f2bf(h0) | ((unsigned)f2bf(h1) << 16);
            }
            int ch = (q * 4 + i) ^ (row & 15);
            *(uint4*)&hnS[br][sbase + ch * 8] = uh;
        }
    }
    __syncthreads();

    // ---- chunked GEMM1 -> GELU -> GEMM2 (K-fused, dbuf chS) ----
    f32x4 a2[2][4];
#pragma unroll
    for (int m = 0; m < 2; ++m)
#pragma unroll
        for (int n = 0; n < 4; ++n) a2[m][n] = z4;

#pragma unroll
    for (int cc = 0; cc < 4; ++cc) {
        // GEMM1 chunk: hid cols cc*64 + wv*32 + n*16 + l15 (n=0..1), K=128
        f32x4 a1[2][2];
#pragma unroll
        for (int m = 0; m < 2; ++m)
#pragma unroll
            for (int n = 0; n < 2; ++n) a1[m][n] = z4;
#pragma unroll
        for (int ks = 0; ks < 4; ++ks) {
            const int ch = (ks * 4 + l4) ^ l15;
            bf16x8 af[2];
#pragma unroll
            for (int m = 0; m < 2; ++m)
                af[m] = *(const bf16x8*)&hnS[br][(m * 16 + l15) * 128 + ch * 8];
#pragma unroll
            for (int n = 0; n < 2; ++n) {
                bf16x8 bfr = *(const bf16x8*)(W1T
                    + (size_t)(cc * 64 + wv * 32 + n * 16 + l15) * 128 + ks * 32 + l4 * 8);
#pragma unroll
                for (int m = 0; m < 2; ++m)
                    a1[m][n] = mfma16(af[m], bfr, a1[m][n]);
            }
        }
        // bias + exact GELU -> swizzled bf16 chunk tile
        u16* chw = &chS[cc & 1][br][0];
#pragma unroll
        for (int n = 0; n < 2; ++n) {
            int cl = wv * 32 + n * 16 + l15;        // local col 0..63
            float bb = b1[cc * 64 + cl];
#pragma unroll
            for (int m = 0; m < 2; ++m)
#pragma unroll
                for (int j = 0; j < 4; ++j) {
                    int r = m * 16 + l4 * 4 + j;
                    float zz = a1[m][n][j] + bb;
                    float g = 0.5f * zz * (1.f + erff(zz * 0.70710678118654752f));
                    chw[r * 64 + (((cl >> 3) ^ (r & 7)) * 8) + (cl & 7)] = f2bf(g);
                }
        }
        __syncthreads();
        // GEMM2 partial: K-slice cc*64..cc*64+63
        const u16* chr = &chS[cc & 1][br][0];
#pragma unroll
        for (int ks2 = 0; ks2 < 2; ++ks2) {
            const int ch8 = (ks2 * 4 + l4) ^ (l15 & 7);
            bf16x8 af[2];
#pragma unroll
            for (int m = 0; m < 2; ++m)
                af[m] = *(const bf16x8*)&chr[(m * 16 + l15) * 64 + ch8 * 8];
#pragma unroll
            for (int n = 0; n < 4; ++n) {
                bf16x8 bfr = *(const bf16x8*)(W2T
                    + (size_t)(wv * 64 + n * 16 + l15) * 256 + cc * 64 + ks2 * 32 + l4 * 8);
#pragma unroll
                for (int m = 0; m < 2; ++m)
                    a2[m][n] = mfma16(af[m], bfr, a2[m][n]);
            }
        }
    }

    // ---- epilogue: spurious stashes to LDS (hnS overlay, dead) + writes
    //      out2; causal writes out0/out1 after sync. ----
    float* sxS = (float*)&hnS[0][0];
    if (br == 1) {
#pragma unroll
        for (int n = 0; n < 4; ++n) {
            int c = wv * 64 + n * 16 + l15;
            float bb = b2[c];
#pragma unroll
            for (int m = 0; m < 2; ++m)
#pragma unroll
                for (int j = 0; j < 4; ++j) {
                    int r = m * 16 + l4 * 4 + j;
                    int ng = n0 + r;
                    float val = a2[m][n][j] + bb;
                    if (ng < N_NODES) {
                        size_t idx = (size_t)ng * 128 + c;
                        val += hat_s[idx];
                        out[2 * TS + outbase + idx] = val;
                    }
                    sxS[r * 128 + c] = val;
                }
        }
    }
    __syncthreads();
    if (br == 0) {
#pragma unroll
        for (int n = 0; n < 4; ++n) {
            int c = wv * 64 + n * 16 + l15;
            float bb = b2[c];
#pragma unroll
            for (int m = 0; m < 2; ++m)
#pragma unroll
                for (int j = 0; j < 4; ++j) {
                    int r = m * 16 + l4 * 4 + j;
                    int ng = n0 + r;
                    if (ng < N_NODES) {
                        size_t idx = (size_t)ng * 128 + c;
                        float val = a2[m][n][j] + bb + hat_c[idx] + xt[idx];
                        float sv = sxS[r * 128 + c];
                        size_t o = outbase + idx;
                        out[o]      = val + sv;
                        out[TS + o] = val;
                    }
                }
        }
    }
}

extern "C" void kernel_launch(void* const* d_in, const int* in_sizes, int n_in,
                              void* d_out, int out_size, void* d_ws, size_t ws_size,
                              hipStream_t stream) {
    const float* x    = (const float*)d_in[0];
    const int*   ei   = (const int*)  d_in[1];
    const float* Wq   = (const float*)d_in[2];
    const float* bq   = (const float*)d_in[3];
    const float* Wk   = (const float*)d_in[4];
    const float* bk   = (const float*)d_in[5];
    const float* Wv   = (const float*)d_in[6];
    const float* bv   = (const float*)d_in[7];
    const float* ln_s = (const float*)d_in[8];
    const float* ln_b = (const float*)d_in[9];
    const float* W1   = (const float*)d_in[10];
    const float* b1   = (const float*)d_in[11];
    const float* W2   = (const float*)d_in[12];
    const float* b2   = (const float*)d_in[13];
    float* out = (float*)d_out;

    // ---- Workspace layout (~274 MB) ----
    const size_t NHID = (size_t)N_NODES * HID;  // 6,400,000
    char* p = (char*)d_ws;
    auto alloc = [&p](size_t bytes) -> void* {
        void* r = (void*)p;
        p += (bytes + 255) & ~(size_t)255;
        return r;
    };
    float* hat_c = (float*)alloc(3 * NHID * 4);   // [t][N][HID]
    float* hat_s = (float*)alloc(3 * NHID * 4);
    int* offs    = (int*)alloc((size_t)T_WIN * (N_NODES + 1) * 4);
    int* cursor  = (int*)alloc((size_t)T_WIN * N_NODES * 4);
    int* srcbuf  = (int*)alloc((size_t)T_WIN * E_PER_T * 4);
    u16* WqTh = (u16*)alloc(128 * 128 * 2);
    u16* WqTl = (u16*)alloc(128 * 128 * 2);
    u16* WkTh = (u16*)alloc(128 * 128 * 2);
    u16* WkTl = (u16*)alloc(128 * 128 * 2);
    u16* WvTh = (u16*)alloc(128 * 128 * 2);
    u16* WvTl = (u16*)alloc(128 * 128 * 2);
    u16* W1T  = (u16*)alloc(128 * 256 * 2);
    u16* W2T  = (u16*)alloc(256 * 128 * 2);
    u16* Qall = (u16*)alloc(3 * NHID * 2);
    u16* Kall = (u16*)alloc(3 * NHID * 2);
    u16* Vall = (u16*)alloc(3 * NHID * 2);

    const int PROJ_BLOCKS = (N_NODES + 63) / 64;          // 782
    const int FFN_BLOCKS  = (N_NODES + 31) / 32;          // 1563
    const int NODE_BLOCKS = (N_NODES + 3) / 4;            // 12500
    const int TN_BLOCKS   = (T_WIN * N_NODES + 255) / 256;
    const int TE_BLOCKS   = (T_WIN * E_PER_T + 255) / 256;

    // ---- weight prep (one dispatch) ----
    {
        dim3 wg(128, 5);
        wprep_kernel<<<wg, 256, 0, stream>>>(
            Wq, Wk, Wv, W1, W2,
            WqTh, WqTl, WkTh, WkTl, WvTh, WvTl, W1T, W2T);
    }

    // ---- CSR build ----
    zero_counts_kernel<<<TN_BLOCKS, 256, 0, stream>>>(cursor);
    hist_kernel<<<TE_BLOCKS, 256, 0, stream>>>(ei, cursor);
    scan_kernel<<<T_WIN, 1024, 0, stream>>>(cursor, offs);
    copy_cursor_kernel<<<TN_BLOCKS, 256, 0, stream>>>(offs, cursor);
    fill_kernel<<<TE_BLOCKS, 256, 0, stream>>>(ei, cursor, srcbuf);

    // ---- all projections (Q/K/V x 3 ts) in one dispatch ----
    {
        dim3 pg(PROJ_BLOCKS, 9);
        project_all_kernel<<<pg, 256, 0, stream>>>(
            x, WqTh, WqTl, bq, WkTh, WkTl, bk, WvTh, WvTl, bv,
            Qall, Kall, Vall);
    }

    // ---- attention, all t in one dispatch ----
    {
        dim3 ag(NODE_BLOCKS, T_WIN);
        attn_fused_kernel<<<ag, 256, 0, stream>>>(
            Qall, Kall, Vall, offs, srcbuf, hat_c, hat_s);
    }

    // ---- FFN + output, all t in one dispatch ----
    {
        dim3 fg(FFN_BLOCKS, T_WIN);
        ffn_out_kernel<<<fg, 256, 0, stream>>>(
            hat_c, hat_s, x, ln_s, ln_b, W1T, b1, W2T, b2, out);
    }
}

// Round 5
// 1030.457 us; speedup vs baseline: 1.5890x; 1.0855x over previous
//
#include <hip/hip_runtime.h>
#include <math.h>

// Problem constants (from reference)
#define T_WIN   3
#define N_NODES 50000
#define HID     128
#define E_PER_T 100000
#define NH      8
#define DK      16
#define CAP     64   // per-node LDS logit cache (avg total degree ~6; slow path covers overflow)

// R9: ffn was traffic-bound by self-inflicted double-reads (FETCH 491MB,
// WRITE 463MB vs 230/230 ideal; 2 TB/s, MfmaUtil 3%). Fix: keep pre-LN rows
// v[32] in regs, route r=a2+b2 through a 32KB fp32 LDS overlay, epilogue in
// LN layout with full-line float4 stores (no hat/x re-read, no write amp).
// attn: LDS cache stores gsrc=ts*N+src; phase C 4-way load prefetch.

typedef unsigned short u16;
typedef __attribute__((ext_vector_type(8))) short bf16x8;   // 8 bf16 = 4 VGPR
typedef __attribute__((ext_vector_type(4))) float f32x4;

__device__ __forceinline__ u16 f2bf(float v) {              // RNE f32->bf16
    unsigned u = __float_as_uint(v);
    return (u16)((u + 0x7fffu + ((u >> 16) & 1u)) >> 16);
}
__device__ __forceinline__ float bf2f(u16 u) {
    return __uint_as_float(((unsigned)u) << 16);
}
__device__ __forceinline__ f32x4 mfma16(bf16x8 a, bf16x8 b, f32x4 c) {
    return __builtin_amdgcn_mfma_f32_16x16x32_bf16(a, b, c, 0, 0, 0);
}

// ---------------------------------------------------------------------------
// Weight prep, ONE dispatch. y=0..2: hi/lo split of Wq/Wk/Wv (128x128);
// y=3: W1 (128x256) bf16; y=4: W2 (256x128) bf16. dst layout [C][R].
// ---------------------------------------------------------------------------
__global__ __launch_bounds__(256) void wprep_kernel(
    const float* __restrict__ Wq, const float* __restrict__ Wk,
    const float* __restrict__ Wv, const float* __restrict__ W1,
    const float* __restrict__ W2,
    u16* __restrict__ WqTh, u16* __restrict__ WqTl,
    u16* __restrict__ WkTh, u16* __restrict__ WkTl,
    u16* __restrict__ WvTh, u16* __restrict__ WvTl,
    u16* __restrict__ W1T, u16* __restrict__ W2T)
{
    const int y = blockIdx.y;
    int i = blockIdx.x * 256 + threadIdx.x;
    if (y < 3) {
        if (i >= 128 * 128) return;
        const float* src = (y == 0) ? Wq : (y == 1) ? Wk : Wv;
        u16* hi = (y == 0) ? WqTh : (y == 1) ? WkTh : WvTh;
        u16* lo = (y == 0) ? WqTl : (y == 1) ? WkTl : WvTl;
        int r = i >> 7, c = i & 127;
        float v = src[i];
        u16 h = f2bf(v);
        hi[c * 128 + r] = h;
        lo[c * 128 + r] = f2bf(v - bf2f(h));
    } else if (y == 3) {
        if (i >= 128 * 256) return;
        int r = i >> 8, c = i & 255;
        W1T[c * 128 + r] = f2bf(W1[i]);
    } else {
        if (i >= 256 * 128) return;
        int r = i >> 7, c = i & 127;
        W2T[c * 256 + r] = f2bf(W2[i]);
    }
}

// ---------------------------------------------------------------------------
// CSR build (once). srcbuf stores SOURCE node ids in CSR order.
// ---------------------------------------------------------------------------
__global__ __launch_bounds__(256) void zero_counts_kernel(int* cursor)
{
    int i = blockIdx.x * 256 + threadIdx.x;
    if (i < T_WIN * N_NODES) cursor[i] = 0;
}

__global__ __launch_bounds__(256) void hist_kernel(
    const int* __restrict__ ei, int* counts)
{
    int i = blockIdx.x * 256 + threadIdx.x;
    if (i >= T_WIN * E_PER_T) return;
    int ts = i / E_PER_T;
    int e  = i - ts * E_PER_T;
    int tar = ei[(ts * 2 + 1) * E_PER_T + e];
    atomicAdd(&counts[ts * N_NODES + tar], 1);
}

__global__ __launch_bounds__(1024) void scan_kernel(
    const int* __restrict__ counts, int* __restrict__ offs)
{
    __shared__ int buf[1024];
    __shared__ int carry;
    const int ts = blockIdx.x;
    const int tid = threadIdx.x;
    if (tid == 0) carry = 0;
    __syncthreads();
    for (int base = 0; base < N_NODES; base += 1024) {
        int i = base + tid;
        int v = (i < N_NODES) ? counts[ts * N_NODES + i] : 0;
        buf[tid] = v;
        __syncthreads();
        for (int o = 1; o < 1024; o <<= 1) {
            int t = (tid >= o) ? buf[tid - o] : 0;
            __syncthreads();
            buf[tid] += t;
            __syncthreads();
        }
        int incl = buf[tid];
        if (i < N_NODES) offs[ts * (N_NODES + 1) + i] = carry + incl - v;
        __syncthreads();
        if (tid == 1023) carry += incl;
        __syncthreads();
    }
    if (tid == 0) offs[ts * (N_NODES + 1) + N_NODES] = carry;
}

__global__ __launch_bounds__(256) void copy_cursor_kernel(
    const int* __restrict__ offs, int* cursor)
{
    int i = blockIdx.x * 256 + threadIdx.x;
    if (i >= T_WIN * N_NODES) return;
    int ts = i / N_NODES;
    int n  = i - ts * N_NODES;
    cursor[i] = offs[ts * (N_NODES + 1) + n];
}

__global__ __launch_bounds__(256) void fill_kernel(
    const int* __restrict__ ei, int* cursor, int* __restrict__ srcbuf)
{
    int i = blockIdx.x * 256 + threadIdx.x;
    if (i >= T_WIN * E_PER_T) return;
    int ts = i / E_PER_T;
    int e  = i - ts * E_PER_T;
    int src = ei[(ts * 2) * E_PER_T + e];
    int tar = ei[(ts * 2 + 1) * E_PER_T + e];
    int pos = atomicAdd(&cursor[ts * N_NODES + tar], 1);
    srcbuf[ts * E_PER_T + pos] = src;
}

// ---------------------------------------------------------------------------
// Split-bf16 MFMA projection, ALL 9 (mat x ts) in one dispatch.
// blockIdx.y: ts = y/3, mat = y%3 (0=Q,1=K,2=V).
// ---------------------------------------------------------------------------
__global__ __launch_bounds__(256) void project_all_kernel(
    const float* __restrict__ x,
    const u16* __restrict__ QTh, const u16* __restrict__ QTl, const float* __restrict__ bq,
    const u16* __restrict__ KTh, const u16* __restrict__ KTl, const float* __restrict__ bk,
    const u16* __restrict__ VTh, const u16* __restrict__ VTl, const float* __restrict__ bv,
    u16* __restrict__ Qall, u16* __restrict__ Kall, u16* __restrict__ Vall)
{
    const int p  = blockIdx.y;
    const int ts = p / 3, mat = p - ts * 3;
    const u16 *WTh, *WTl; const float* b; u16* O;
    if (mat == 0)      { WTh = QTh; WTl = QTl; b = bq; O = Qall; }
    else if (mat == 1) { WTh = KTh; WTl = KTl; b = bk; O = Kall; }
    else               { WTh = VTh; WTl = VTl; b = bv; O = Vall; }
    const size_t NHID = (size_t)N_NODES * HID;
    const float* __restrict__ xs = x + (size_t)ts * NHID;
    O += (size_t)ts * NHID;

    __shared__ u16 xhS[64 * 128];
    __shared__ u16 xlS[64 * 128];
    const int tid = threadIdx.x;
    const int n0 = blockIdx.x * 64;

    {   // stage: 4 threads/row, each covers 32 cols; hi/lo split, swizzled
        const int row = tid >> 2, q = tid & 3;
        const int n = n0 + row;
        const float4* xp = (const float4*)(xs + (size_t)n * 128 + q * 32);
        const int sbase = row * 128;
#pragma unroll
        for (int i = 0; i < 4; ++i) {
            float4 a = make_float4(0.f, 0.f, 0.f, 0.f), c = a;
            if (n < N_NODES) { a = xp[2 * i]; c = xp[2 * i + 1]; }
            float vv[8] = {a.x, a.y, a.z, a.w, c.x, c.y, c.z, c.w};
            uint4 uh, ul;
            unsigned* ph = (unsigned*)&uh;
            unsigned* pl = (unsigned*)&ul;
#pragma unroll
            for (int j = 0; j < 4; ++j) {
                u16 h0 = f2bf(vv[2 * j]), h1 = f2bf(vv[2 * j + 1]);
                ph[j] = (unsigned)h0 | ((unsigned)h1 << 16);
                u16 l0 = f2bf(vv[2 * j] - bf2f(h0));
                u16 l1 = f2bf(vv[2 * j + 1] - bf2f(h1));
                pl[j] = (unsigned)l0 | ((unsigned)l1 << 16);
            }
            int ch = (q * 4 + i) ^ (row & 15);
            *(uint4*)&xhS[sbase + ch * 8] = uh;
            *(uint4*)&xlS[sbase + ch * 8] = ul;
        }
    }
    __syncthreads();

    const int lane = tid & 63, w = tid >> 6;
    const int l15 = lane & 15, l4 = lane >> 4;
    f32x4 acc[4][2];
    const f32x4 z4 = {0.f, 0.f, 0.f, 0.f};
#pragma unroll
    for (int m = 0; m < 4; ++m)
#pragma unroll
        for (int n = 0; n < 2; ++n) acc[m][n] = z4;

#pragma unroll
    for (int ks = 0; ks < 4; ++ks) {
        const int ch = (ks * 4 + l4) ^ l15;
        bf16x8 ah[4], al[4];
#pragma unroll
        for (int m = 0; m < 4; ++m) {
            ah[m] = *(const bf16x8*)&xhS[(m * 16 + l15) * 128 + ch * 8];
            al[m] = *(const bf16x8*)&xlS[(m * 16 + l15) * 128 + ch * 8];
        }
        bf16x8 bh[2], bl[2];
#pragma unroll
        for (int n = 0; n < 2; ++n) {
            size_t wo = (size_t)(w * 32 + n * 16 + l15) * 128 + ks * 32 + l4 * 8;
            bh[n] = *(const bf16x8*)(WTh + wo);
            bl[n] = *(const bf16x8*)(WTl + wo);
        }
#pragma unroll
        for (int m = 0; m < 4; ++m)
#pragma unroll
            for (int n = 0; n < 2; ++n) {
                acc[m][n] = mfma16(ah[m], bh[n], acc[m][n]);
                acc[m][n] = mfma16(ah[m], bl[n], acc[m][n]);
                acc[m][n] = mfma16(al[m], bh[n], acc[m][n]);
            }
    }

    // C/D: col = lane&15, row = (lane>>4)*4 + reg
#pragma unroll
    for (int n = 0; n < 2; ++n) {
        int c = w * 32 + n * 16 + l15;
        float bb = b[c];
#pragma unroll
        for (int m = 0; m < 4; ++m)
#pragma unroll
            for (int j = 0; j < 4; ++j) {
                int r = m * 16 + l4 * 4 + j;
                int ng = n0 + r;
                if (ng < N_NODES)
                    O[(size_t)ng * 128 + c] = f2bf(acc[m][n][j] + bb);
            }
    }
}

// ---------------------------------------------------------------------------
// Fused attention, ALL t in one dispatch (blockIdx.y = t_tar).
// One wave per node. Phase A: logits (LDS cache: logit + gsrc=ts*N+src) +
// max/min; Phase B: exp sums; Phase C: flattened 4-way-prefetched V
// accumulate, single hat write. Slow path covers degree > CAP.
// ---------------------------------------------------------------------------
__global__ __launch_bounds__(256) void attn_fused_kernel(
    const u16* __restrict__ Qall, const u16* __restrict__ Kall,
    const u16* __restrict__ Vall,
    const int* __restrict__ offs, const int* __restrict__ srcbuf,
    float* __restrict__ hat_c_all, float* __restrict__ hat_s_all)
{
    __shared__ float logitS[4][CAP][NH];
    __shared__ int   srcS[4][CAP];
    const int t_tar = blockIdx.y;
    const int lane = threadIdx.x & 63;
    const int wave = threadIdx.x >> 6;
    const int node = blockIdx.x * 4 + wave;
    if (node >= N_NODES) return;

    const size_t NHID = (size_t)N_NODES * HID;
    float* __restrict__ hat_c = hat_c_all + (size_t)t_tar * NHID;
    float* __restrict__ hat_s = hat_s_all + (size_t)t_tar * NHID;
    const u16* __restrict__ Qt = Qall + (size_t)t_tar * NHID;
    const int h  = lane & 7;      // phase A/B: head
    const int j8 = lane >> 3;     // phase A/B: edge slot

    float (*lg)[NH] = logitS[wave];
    int* sx = srcS[wave];

    uint4 q0, q1;
    {
        const uint4* qp = (const uint4*)(Qt + (size_t)node * HID + h * DK);
        q0 = qp[0]; q1 = qp[1];
    }

    // ---- Phase A: logits + max/min + LDS cache (gsrc = ts*N + src) ----
    float mx = -1e30f, mn = 1e30f;
    int base = 0;
    for (int ts = 0; ts <= t_tar; ++ts) {
        const int beg = offs[ts * (N_NODES + 1) + node];
        const int end = offs[ts * (N_NODES + 1) + node + 1];
        const u16* __restrict__ K = Kall + (size_t)ts * NHID;
        const int* __restrict__ sb = srcbuf + (size_t)ts * E_PER_T;
        for (int j = beg + j8; j < end; j += 8) {
            int idx = base + (j - beg);
            int src = sb[j];
            const uint4* kp = (const uint4*)(K + (size_t)src * HID + h * DK);
            uint4 k0 = kp[0], k1 = kp[1];
            float s = 0.f;
            const unsigned* pa = (const unsigned*)&q0;
            const unsigned* pb = (const unsigned*)&k0;
#pragma unroll
            for (int i = 0; i < 4; ++i)
                s += __uint_as_float(pa[i] << 16) * __uint_as_float(pb[i] << 16)
                   + __uint_as_float(pa[i] & 0xffff0000u) * __uint_as_float(pb[i] & 0xffff0000u);
            pa = (const unsigned*)&q1; pb = (const unsigned*)&k1;
#pragma unroll
            for (int i = 0; i < 4; ++i)
                s += __uint_as_float(pa[i] << 16) * __uint_as_float(pb[i] << 16)
                   + __uint_as_float(pa[i] & 0xffff0000u) * __uint_as_float(pb[i] & 0xffff0000u);
            s *= 0.25f;  // / sqrt(16)
            mx = fmaxf(mx, s);
            mn = fminf(mn, s);
            if (idx < CAP) { lg[idx][h] = s; if (h == 0) sx[idx] = ts * N_NODES + src; }
        }
        base += end - beg;
    }
    const int dtot = base;
    if (dtot == 0) {
        size_t bidx = (size_t)node * HID + 2 * lane;
        *(float2*)(hat_c + bidx) = make_float2(0.f, 0.f);
        *(float2*)(hat_s + bidx) = make_float2(0.f, 0.f);
        return;
    }
#pragma unroll
    for (int o = 8; o < 64; o <<= 1) {
        mx = fmaxf(mx, __shfl_xor(mx, o));
        mn = fminf(mn, __shfl_xor(mn, o));
    }

    // ---- Phase B: exp sums ----
    float sc = 0.f, ss = 0.f;
    {
        const int nfast = dtot < CAP ? dtot : CAP;
        for (int idx = j8; idx < nfast; idx += 8) {
            float a = lg[idx][h];
            sc += __expf(a - mx);
            ss += __expf(mn - a);
        }
        if (dtot > CAP) {
            int b2 = 0;
            for (int ts = 0; ts <= t_tar; ++ts) {
                const int beg = offs[ts * (N_NODES + 1) + node];
                const int end = offs[ts * (N_NODES + 1) + node + 1];
                const u16* K = Kall + (size_t)ts * NHID;
                const int* sb = srcbuf + (size_t)ts * E_PER_T;
                for (int j = beg + j8; j < end; j += 8) {
                    int idx = b2 + (j - beg);
                    if (idx >= CAP) {
                        int src = sb[j];
                        const uint4* kp = (const uint4*)(K + (size_t)src * HID + h * DK);
                        uint4 k0 = kp[0], k1 = kp[1];
                        float s = 0.f;
                        const unsigned* pa = (const unsigned*)&q0;
                        const unsigned* pb = (const unsigned*)&k0;
#pragma unroll
                        for (int i = 0; i < 4; ++i)
                            s += __uint_as_float(pa[i] << 16) * __uint_as_float(pb[i] << 16)
                               + __uint_as_float(pa[i] & 0xffff0000u) * __uint_as_float(pb[i] & 0xffff0000u);
                        pa = (const unsigned*)&q1; pb = (const unsigned*)&k1;
#pragma unroll
                        for (int i = 0; i < 4; ++i)
                            s += __uint_as_float(pa[i] << 16) * __uint_as_float(pb[i] << 16)
                               + __uint_as_float(pa[i] & 0xffff0000u) * __uint_as_float(pb[i] & 0xffff0000u);
                        s *= 0.25f;
                        sc += __expf(s - mx);
                        ss += __expf(mn - s);
                    }
                }
                b2 += end - beg;
            }
        }
    }
#pragma unroll
    for (int o = 8; o < 64; o <<= 1) {
        sc += __shfl_xor(sc, o);
        ss += __shfl_xor(ss, o);
    }

    // ---- Phase C: V accumulate (lane owns dims 2l,2l+1; head = lane>>3) ----
    const int h2 = lane >> 3;
    const float mc   = __shfl(mx, h2);
    const float mnn  = __shfl(mn, h2);
    const float isc  = 1.f / (__shfl(sc, h2) + 1e-16f);
    const float iss  = 1.f / (__shfl(ss, h2) + 1e-16f);

    float aC0 = 0.f, aC1 = 0.f, aS0 = 0.f, aS1 = 0.f;
    if (dtot <= CAP) {
        // fast: flattened LDS edge list, groups of 4 with prefetched loads
        const int dl = 2 * lane;
        for (int i0 = 0; i0 < dtot; i0 += 4) {
            int i1 = i0 + 1, i2 = i0 + 2, i3 = i0 + 3;
            int k1 = (i1 < dtot) ? i1 : i0;
            int k2 = (i2 < dtot) ? i2 : i0;
            int k3 = (i3 < dtot) ? i3 : i0;
            float a0 = lg[i0][h2], a1 = lg[k1][h2];
            float a2 = lg[k2][h2], a3 = lg[k3][h2];
            int g0 = sx[i0], g1 = sx[k1], g2 = sx[k2], g3 = sx[k3];
            unsigned w0 = *(const unsigned*)(Vall + (size_t)g0 * HID + dl);
            unsigned w1 = *(const unsigned*)(Vall + (size_t)g1 * HID + dl);
            unsigned w2 = *(const unsigned*)(Vall + (size_t)g2 * HID + dl);
            unsigned w3 = *(const unsigned*)(Vall + (size_t)g3 * HID + dl);
            float f1 = (i1 < dtot) ? 1.f : 0.f;
            float f2 = (i2 < dtot) ? 1.f : 0.f;
            float f3 = (i3 < dtot) ? 1.f : 0.f;
            {
                float pc = __expf(a0 - mc) * isc, ps = __expf(mnn - a0) * iss;
                float v0 = __uint_as_float(w0 << 16);
                float v1 = __uint_as_float(w0 & 0xffff0000u);
                aC0 += v0 * pc; aC1 += v1 * pc; aS0 += v0 * ps; aS1 += v1 * ps;
            }
            {
                float pc = __expf(a1 - mc) * isc * f1, ps = __expf(mnn - a1) * iss * f1;
                float v0 = __uint_as_float(w1 << 16);
                float v1 = __uint_as_float(w1 & 0xffff0000u);
                aC0 += v0 * pc; aC1 += v1 * pc; aS0 += v0 * ps; aS1 += v1 * ps;
            }
            {
                float pc = __expf(a2 - mc) * isc * f2, ps = __expf(mnn - a2) * iss * f2;
                float v0 = __uint_as_float(w2 << 16);
                float v1 = __uint_as_float(w2 & 0xffff0000u);
                aC0 += v0 * pc; aC1 += v1 * pc; aS0 += v0 * ps; aS1 += v1 * ps;
            }
            {
                float pc = __expf(a3 - mc) * isc * f3, ps = __expf(mnn - a3) * iss * f3;
                float v0 = __uint_as_float(w3 << 16);
                float v1 = __uint_as_float(w3 & 0xffff0000u);
                aC0 += v0 * pc; aC1 += v1 * pc; aS0 += v0 * ps; aS1 += v1 * ps;
            }
        }
    } else {
        // slow: original CSR walk (rare)
        int b2 = 0;
        for (int ts = 0; ts <= t_tar; ++ts) {
            const int beg = offs[ts * (N_NODES + 1) + node];
            const int end = offs[ts * (N_NODES + 1) + node + 1];
            const int* __restrict__ sb = srcbuf + (size_t)ts * E_PER_T;
            for (int j = beg; j < end; ++j) {
                int idx = b2 + (j - beg);
                float a; size_t gaddr;
                if (idx < CAP) {
                    a = lg[idx][h2];
                    gaddr = (size_t)sx[idx] * HID;
                } else {
                    int src = sb[j];
                    gaddr = ((size_t)ts * N_NODES + src) * HID;
                    unsigned qd = *(const unsigned*)(Qt + (size_t)node * HID + 2 * lane);
                    unsigned kd = *(const unsigned*)(Kall + gaddr + 2 * lane);
                    float p = __uint_as_float(qd << 16) * __uint_as_float(kd << 16)
                            + __uint_as_float(qd & 0xffff0000u) * __uint_as_float(kd & 0xffff0000u);
                    p += __shfl_xor(p, 1);
                    p += __shfl_xor(p, 2);
                    p += __shfl_xor(p, 4);
                    a = p * 0.25f;
                }
                float pc = __expf(a - mc) * isc;
                float ps = __expf(mnn - a) * iss;
                unsigned v2 = *(const unsigned*)(Vall + gaddr + 2 * lane);
                float v0 = __uint_as_float(v2 << 16);
                float v1 = __uint_as_float(v2 & 0xffff0000u);
                aC0 += v0 * pc; aC1 += v1 * pc;
                aS0 += v0 * ps; aS1 += v1 * ps;
            }
            b2 += end - beg;
        }
    }
    size_t bidx = (size_t)node * HID + 2 * lane;
    *(float2*)(hat_c + bidx) = make_float2(aC0, aC1);
    *(float2*)(hat_s + bidx) = make_float2(aS0, aS1);
}

// ---------------------------------------------------------------------------
// FFN via MFMA, ALL t (blockIdx.y = t), branches parallel across waves,
// 32-node tile. Pre-LN rows v[32] stay in REGISTERS; after the chunked
// GEMM1->GELU->GEMM2 pipeline, r=a2+b2 goes through a 32KB fp32 LDS overlay
// (hnS+chS dead) and the LN-layout threads emit out0/1/2 as full-line
// float4 stores. No hat/x re-read, no write amplification.
// ---------------------------------------------------------------------------
__global__ __launch_bounds__(256, 4) void ffn_out_kernel(
    const float* __restrict__ hat_c_all, const float* __restrict__ hat_s_all,
    const float* __restrict__ x,
    const float* __restrict__ ln_s, const float* __restrict__ ln_b,
    const u16* __restrict__ W1T, const float* __restrict__ b1,
    const u16* __restrict__ W2T, const float* __restrict__ b2,
    float* __restrict__ out)
{
    __shared__ char ldsbuf[32768];
    u16* hnS = (u16*)ldsbuf;                 // [2][32*128] bf16 (16 KB)
    u16* chS = (u16*)(ldsbuf + 16384);       // [2][2][32*64] bf16 (16 KB)
    float* rS = (float*)ldsbuf;              // [2][32][128] f32 overlay (32 KB)

    const int t_tar = blockIdx.y;
    const int n0 = blockIdx.x * 32;
    const int tid = threadIdx.x;
    const size_t NHID = (size_t)N_NODES * HID;
    const float* __restrict__ hat_c = hat_c_all + (size_t)t_tar * NHID;
    const float* __restrict__ hat_s = hat_s_all + (size_t)t_tar * NHID;
    const float* __restrict__ xt = x + (size_t)t_tar * NHID;
    const size_t TS = (size_t)T_WIN * N_NODES * HID;
    const size_t outbase = (size_t)t_tar * NHID;

    const int lane = tid & 63;
    const int wave = tid >> 6;
    const int br   = wave >> 1;          // GEMM branch: 0 causal, 1 spurious
    const int wv   = wave & 1;           // wave-within-branch
    const int l15 = lane & 15, l4 = lane >> 4;
    const f32x4 z4 = {0.f, 0.f, 0.f, 0.f};

    // LN/epilogue mapping: brL = tid>>7 (== br), 4 threads/row, 32 cols each
    const int brL = tid >> 7;
    const int rowL = (tid & 127) >> 2, qL = tid & 3;
    const int nL = n0 + rowL;
    const float* __restrict__ hatL = brL ? hat_s : hat_c;

    float v[32];   // pre-LN row segment (hat [+x]) -- LIVE through GEMMs

    // ---- LayerNorm ----
    {
        float s = 0.f, s2 = 0.f;
        if (nL < N_NODES) {
            const float4* hp = (const float4*)(hatL + (size_t)nL * 128 + qL * 32);
            const float4* xp = (const float4*)(xt + (size_t)nL * 128 + qL * 32);
#pragma unroll
            for (int i = 0; i < 8; ++i) {
                float4 a = hp[i];
                if (brL == 0) {
                    float4 bx = xp[i];
                    a.x += bx.x; a.y += bx.y; a.z += bx.z; a.w += bx.w;
                }
                v[4 * i] = a.x; v[4 * i + 1] = a.y;
                v[4 * i + 2] = a.z; v[4 * i + 3] = a.w;
                s  += a.x + a.y + a.z + a.w;
                s2 += a.x * a.x + a.y * a.y + a.z * a.z + a.w * a.w;
            }
        } else {
#pragma unroll
            for (int i = 0; i < 32; ++i) v[i] = 0.f;
        }
        s  += __shfl_xor(s, 1);  s  += __shfl_xor(s, 2);
        s2 += __shfl_xor(s2, 1); s2 += __shfl_xor(s2, 2);
        float mu  = s * (1.f / 128.f);
        float var = s2 * (1.f / 128.f) - mu * mu;
        float rstd = rsqrtf(var + 1e-5f);
        const int sbase = brL * 4096 + rowL * 128;
#pragma unroll
        for (int i = 0; i < 4; ++i) {
            uint4 uh; unsigned* ph = (unsigned*)&uh;
#pragma unroll
            for (int j = 0; j < 4; ++j) {
                int c0 = qL * 32 + i * 8 + 2 * j;
                float h0 = (v[i * 8 + 2 * j]     - mu) * rstd * ln_s[c0]     + ln_b[c0];
                float h1 = (v[i * 8 + 2 * j + 1] - mu) * rstd * ln_s[c0 + 1] + ln_b[c0 + 1];
                if (nL >= N_NODES) { h0 = 0.f; h1 = 0.f; }
                ph[j] = (unsigned)f2bf(h0) | ((unsigned)f2bf(h1) << 16);
            }
            int ch = (qL * 4 + i) ^ (rowL & 15);
            *(uint4*)&hnS[sbase + ch * 8] = uh;
        }
    }
    __syncthreads();

    // ---- chunked GEMM1 -> GELU -> GEMM2 (K-fused, dbuf chS) ----
    f32x4 a2[2][4];
#pragma unroll
    for (int m = 0; m < 2; ++m)
#pragma unroll
        for (int n = 0; n < 4; ++n) a2[m][n] = z4;

#pragma unroll
    for (int cc = 0; cc < 4; ++cc) {
        f32x4 a1[2][2];
#pragma unroll
        for (int m = 0; m < 2; ++m)
#pragma unroll
            for (int n = 0; n < 2; ++n) a1[m][n] = z4;
#pragma unroll
        for (int ks = 0; ks < 4; ++ks) {
            const int ch = (ks * 4 + l4) ^ l15;
            bf16x8 af[2];
#pragma unroll
            for (int m = 0; m < 2; ++m)
                af[m] = *(const bf16x8*)&hnS[br * 4096 + (m * 16 + l15) * 128 + ch * 8];
#pragma unroll
            for (int n = 0; n < 2; ++n) {
                bf16x8 bfr = *(const bf16x8*)(W1T
                    + (size_t)(cc * 64 + wv * 32 + n * 16 + l15) * 128 + ks * 32 + l4 * 8);
#pragma unroll
                for (int m = 0; m < 2; ++m)
                    a1[m][n] = mfma16(af[m], bfr, a1[m][n]);
            }
        }
        // bias + exact GELU -> swizzled bf16 chunk tile
        u16* chw = chS + ((cc & 1) * 2 + br) * (32 * 64);
#pragma unroll
        for (int n = 0; n < 2; ++n) {
            int cl = wv * 32 + n * 16 + l15;        // local col 0..63
            float bb = b1[cc * 64 + cl];
#pragma unroll
            for (int m = 0; m < 2; ++m)
#pragma unroll
                for (int j = 0; j < 4; ++j) {
                    int r = m * 16 + l4 * 4 + j;
                    float zz = a1[m][n][j] + bb;
                    float g = 0.5f * zz * (1.f + erff(zz * 0.70710678118654752f));
                    chw[r * 64 + (((cl >> 3) ^ (r & 7)) * 8) + (cl & 7)] = f2bf(g);
                }
        }
        __syncthreads();
        // GEMM2 partial: K-slice cc*64..cc*64+63
        const u16* chr = chS + ((cc & 1) * 2 + br) * (32 * 64);
#pragma unroll
        for (int ks2 = 0; ks2 < 2; ++ks2) {
            const int ch8 = (ks2 * 4 + l4) ^ (l15 & 7);
            bf16x8 af[2];
#pragma unroll
            for (int m = 0; m < 2; ++m)
                af[m] = *(const bf16x8*)&chr[(m * 16 + l15) * 64 + ch8 * 8];
#pragma unroll
            for (int n = 0; n < 4; ++n) {
                bf16x8 bfr = *(const bf16x8*)(W2T
                    + (size_t)(wv * 64 + n * 16 + l15) * 256 + cc * 64 + ks2 * 32 + l4 * 8);
#pragma unroll
                for (int m = 0; m < 2; ++m)
                    a2[m][n] = mfma16(af[m], bfr, a2[m][n]);
            }
        }
    }
    __syncthreads();   // hnS + chS now dead -> rS overlay is safe

    // ---- r = a2 + b2 -> LDS (XOR-swizzled fp32) ----
#pragma unroll
    for (int n = 0; n < 4; ++n) {
        int c = wv * 64 + n * 16 + l15;
        float bb = b2[c];
#pragma unroll
        for (int m = 0; m < 2; ++m)
#pragma unroll
            for (int j = 0; j < 4; ++j) {
                int r = m * 16 + l4 * 4 + j;
                rS[br * 4096 + r * 128 + (c ^ ((r & 7) << 2))] = a2[m][n][j] + bb;
            }
    }
    __syncthreads();

    // ---- epilogue in LN layout: val = v + r; full-line float4 stores ----
    const int swzL = (rowL & 7) << 2;
    {
#pragma unroll
        for (int i = 0; i < 8; ++i) {
            float4 rv = *(const float4*)&rS[brL * 4096 + rowL * 128
                                            + ((qL * 32 + i * 4) ^ swzL)];
            v[4 * i]     += rv.x; v[4 * i + 1] += rv.y;
            v[4 * i + 2] += rv.z; v[4 * i + 3] += rv.w;
        }
    }
    if (brL == 1) {
        if (nL < N_NODES) {
            float* o2 = out + 2 * TS + outbase + (size_t)nL * 128 + qL * 32;
#pragma unroll
            for (int i = 0; i < 8; ++i)
                *(float4*)&o2[i * 4] = make_float4(v[4 * i], v[4 * i + 1],
                                                   v[4 * i + 2], v[4 * i + 3]);
        }
        // stash spurious result for causal threads (same addresses)
#pragma unroll
        for (int i = 0; i < 8; ++i)
            *(float4*)&rS[4096 + rowL * 128 + ((qL * 32 + i * 4) ^ swzL)] =
                make_float4(v[4 * i], v[4 * i + 1], v[4 * i + 2], v[4 * i + 3]);
    }
    __syncthreads();
    if (brL == 0 && nL < N_NODES) {
        float* o0 = out + outbase + (size_t)nL * 128 + qL * 32;
        float* o1 = out + TS + outbase + (size_t)nL * 128 + qL * 32;
#pragma unroll
        for (int i = 0; i < 8; ++i) {
            float4 sv = *(const float4*)&rS[4096 + rowL * 128
                                            + ((qL * 32 + i * 4) ^ swzL)];
            float4 cv = make_float4(v[4 * i], v[4 * i + 1], v[4 * i + 2], v[4 * i + 3]);
            *(float4*)&o1[i * 4] = cv;
            *(float4*)&o0[i * 4] = make_float4(cv.x + sv.x, cv.y + sv.y,
                                               cv.z + sv.z, cv.w + sv.w);
        }
    }
}

extern "C" void kernel_launch(void* const* d_in, const int* in_sizes, int n_in,
                              void* d_out, int out_size, void* d_ws, size_t ws_size,
                              hipStream_t stream) {
    const float* x    = (const float*)d_in[0];
    const int*   ei   = (const int*)  d_in[1];
    const float* Wq   = (const float*)d_in[2];
    const float* bq   = (const float*)d_in[3];
    const float* Wk   = (const float*)d_in[4];
    const float* bk   = (const float*)d_in[5];
    const float* Wv   = (const float*)d_in[6];
    const float* bv   = (const float*)d_in[7];
    const float* ln_s = (const float*)d_in[8];
    const float* ln_b = (const float*)d_in[9];
    const float* W1   = (const float*)d_in[10];
    const float* b1   = (const float*)d_in[11];
    const float* W2   = (const float*)d_in[12];
    const float* b2   = (const float*)d_in[13];
    float* out = (float*)d_out;

    // ---- Workspace layout (~274 MB) ----
    const size_t NHID = (size_t)N_NODES * HID;  // 6,400,000
    char* p = (char*)d_ws;
    auto alloc = [&p](size_t bytes) -> void* {
        void* r = (void*)p;
        p += (bytes + 255) & ~(size_t)255;
        return r;
    };
    float* hat_c = (float*)alloc(3 * NHID * 4);   // [t][N][HID]
    float* hat_s = (float*)alloc(3 * NHID * 4);
    int* offs    = (int*)alloc((size_t)T_WIN * (N_NODES + 1) * 4);
    int* cursor  = (int*)alloc((size_t)T_WIN * N_NODES * 4);
    int* srcbuf  = (int*)alloc((size_t)T_WIN * E_PER_T * 4);
    u16* WqTh = (u16*)alloc(128 * 128 * 2);
    u16* WqTl = (u16*)alloc(128 * 128 * 2);
    u16* WkTh = (u16*)alloc(128 * 128 * 2);
    u16* WkTl = (u16*)alloc(128 * 128 * 2);
    u16* WvTh = (u16*)alloc(128 * 128 * 2);
    u16* WvTl = (u16*)alloc(128 * 128 * 2);
    u16* W1T  = (u16*)alloc(128 * 256 * 2);
    u16* W2T  = (u16*)alloc(256 * 128 * 2);
    u16* Qall = (u16*)alloc(3 * NHID * 2);
    u16* Kall = (u16*)alloc(3 * NHID * 2);
    u16* Vall = (u16*)alloc(3 * NHID * 2);

    const int PROJ_BLOCKS = (N_NODES + 63) / 64;          // 782
    const int FFN_BLOCKS  = (N_NODES + 31) / 32;          // 1563
    const int NODE_BLOCKS = (N_NODES + 3) / 4;            // 12500
    const int TN_BLOCKS   = (T_WIN * N_NODES + 255) / 256;
    const int TE_BLOCKS   = (T_WIN * E_PER_T + 255) / 256;

    // ---- weight prep (one dispatch) ----
    {
        dim3 wg(128, 5);
        wprep_kernel<<<wg, 256, 0, stream>>>(
            Wq, Wk, Wv, W1, W2,
            WqTh, WqTl, WkTh, WkTl, WvTh, WvTl, W1T, W2T);
    }

    // ---- CSR build ----
    zero_counts_kernel<<<TN_BLOCKS, 256, 0, stream>>>(cursor);
    hist_kernel<<<TE_BLOCKS, 256, 0, stream>>>(ei, cursor);
    scan_kernel<<<T_WIN, 1024, 0, stream>>>(cursor, offs);
    copy_cursor_kernel<<<TN_BLOCKS, 256, 0, stream>>>(offs, cursor);
    fill_kernel<<<TE_BLOCKS, 256, 0, stream>>>(ei, cursor, srcbuf);

    // ---- all projections (Q/K/V x 3 ts) in one dispatch ----
    {
        dim3 pg(PROJ_BLOCKS, 9);
        project_all_kernel<<<pg, 256, 0, stream>>>(
            x, WqTh, WqTl, bq, WkTh, WkTl, bk, WvTh, WvTl, bv,
            Qall, Kall, Vall);
    }

    // ---- attention, all t in one dispatch ----
    {
        dim3 ag(NODE_BLOCKS, T_WIN);
        attn_fused_kernel<<<ag, 256, 0, stream>>>(
            Qall, Kall, Vall, offs, srcbuf, hat_c, hat_s);
    }

    // ---- FFN + output, all t in one dispatch ----
    {
        dim3 fg(FFN_BLOCKS, T_WIN);
        ffn_out_kernel<<<fg, 256, 0, stream>>>(
            hat_c, hat_s, x, ln_s, ln_b, W1T, b1, W2T, b2, out);
    }
}

// Round 6
// 1003.989 us; speedup vs baseline: 1.6309x; 1.0264x over previous
//
#include <hip/hip_runtime.h>
#include <math.h>

// Problem constants (from reference)
#define T_WIN   3
#define N_NODES 50000
#define HID     128
#define E_PER_T 100000
#define NH      8
#define DK      16
#define CAP     64   // per-node LDS logit cache (avg total degree ~6; slow path covers overflow)

// R10: ffn FETCH was 2x ideal (461MB = 230 reads + 230 out write-allocate),
// WRITE 533MB: epilogue float4 stores were 16B-per-128B-stride partial-sector
// writes -> RMW amplification. Fix: fold val=v+r into rS in place, then a
// streaming store phase copies each 16KB tile with fully-contiguous
// 1KB-per-wave-instruction stores (out1=rS[0], out2=rS[1], out0=sum).

typedef unsigned short u16;
typedef __attribute__((ext_vector_type(8))) short bf16x8;   // 8 bf16 = 4 VGPR
typedef __attribute__((ext_vector_type(4))) float f32x4;

__device__ __forceinline__ u16 f2bf(float v) {              // RNE f32->bf16
    unsigned u = __float_as_uint(v);
    return (u16)((u + 0x7fffu + ((u >> 16) & 1u)) >> 16);
}
__device__ __forceinline__ float bf2f(u16 u) {
    return __uint_as_float(((unsigned)u) << 16);
}
__device__ __forceinline__ f32x4 mfma16(bf16x8 a, bf16x8 b, f32x4 c) {
    return __builtin_amdgcn_mfma_f32_16x16x32_bf16(a, b, c, 0, 0, 0);
}

// ---------------------------------------------------------------------------
// Weight prep, ONE dispatch. y=0..2: hi/lo split of Wq/Wk/Wv (128x128);
// y=3: W1 (128x256) bf16; y=4: W2 (256x128) bf16. dst layout [C][R].
// ---------------------------------------------------------------------------
__global__ __launch_bounds__(256) void wprep_kernel(
    const float* __restrict__ Wq, const float* __restrict__ Wk,
    const float* __restrict__ Wv, const float* __restrict__ W1,
    const float* __restrict__ W2,
    u16* __restrict__ WqTh, u16* __restrict__ WqTl,
    u16* __restrict__ WkTh, u16* __restrict__ WkTl,
    u16* __restrict__ WvTh, u16* __restrict__ WvTl,
    u16* __restrict__ W1T, u16* __restrict__ W2T)
{
    const int y = blockIdx.y;
    int i = blockIdx.x * 256 + threadIdx.x;
    if (y < 3) {
        if (i >= 128 * 128) return;
        const float* src = (y == 0) ? Wq : (y == 1) ? Wk : Wv;
        u16* hi = (y == 0) ? WqTh : (y == 1) ? WkTh : WvTh;
        u16* lo = (y == 0) ? WqTl : (y == 1) ? WkTl : WvTl;
        int r = i >> 7, c = i & 127;
        float v = src[i];
        u16 h = f2bf(v);
        hi[c * 128 + r] = h;
        lo[c * 128 + r] = f2bf(v - bf2f(h));
    } else if (y == 3) {
        if (i >= 128 * 256) return;
        int r = i >> 8, c = i & 255;
        W1T[c * 128 + r] = f2bf(W1[i]);
    } else {
        if (i >= 256 * 128) return;
        int r = i >> 7, c = i & 127;
        W2T[c * 256 + r] = f2bf(W2[i]);
    }
}

// ---------------------------------------------------------------------------
// CSR build (once). srcbuf stores SOURCE node ids in CSR order.
// ---------------------------------------------------------------------------
__global__ __launch_bounds__(256) void zero_counts_kernel(int* cursor)
{
    int i = blockIdx.x * 256 + threadIdx.x;
    if (i < T_WIN * N_NODES) cursor[i] = 0;
}

__global__ __launch_bounds__(256) void hist_kernel(
    const int* __restrict__ ei, int* counts)
{
    int i = blockIdx.x * 256 + threadIdx.x;
    if (i >= T_WIN * E_PER_T) return;
    int ts = i / E_PER_T;
    int e  = i - ts * E_PER_T;
    int tar = ei[(ts * 2 + 1) * E_PER_T + e];
    atomicAdd(&counts[ts * N_NODES + tar], 1);
}

__global__ __launch_bounds__(1024) void scan_kernel(
    const int* __restrict__ counts, int* __restrict__ offs)
{
    __shared__ int buf[1024];
    __shared__ int carry;
    const int ts = blockIdx.x;
    const int tid = threadIdx.x;
    if (tid == 0) carry = 0;
    __syncthreads();
    for (int base = 0; base < N_NODES; base += 1024) {
        int i = base + tid;
        int v = (i < N_NODES) ? counts[ts * N_NODES + i] : 0;
        buf[tid] = v;
        __syncthreads();
        for (int o = 1; o < 1024; o <<= 1) {
            int t = (tid >= o) ? buf[tid - o] : 0;
            __syncthreads();
            buf[tid] += t;
            __syncthreads();
        }
        int incl = buf[tid];
        if (i < N_NODES) offs[ts * (N_NODES + 1) + i] = carry + incl - v;
        __syncthreads();
        if (tid == 1023) carry += incl;
        __syncthreads();
    }
    if (tid == 0) offs[ts * (N_NODES + 1) + N_NODES] = carry;
}

__global__ __launch_bounds__(256) void copy_cursor_kernel(
    const int* __restrict__ offs, int* cursor)
{
    int i = blockIdx.x * 256 + threadIdx.x;
    if (i >= T_WIN * N_NODES) return;
    int ts = i / N_NODES;
    int n  = i - ts * N_NODES;
    cursor[i] = offs[ts * (N_NODES + 1) + n];
}

__global__ __launch_bounds__(256) void fill_kernel(
    const int* __restrict__ ei, int* cursor, int* __restrict__ srcbuf)
{
    int i = blockIdx.x * 256 + threadIdx.x;
    if (i >= T_WIN * E_PER_T) return;
    int ts = i / E_PER_T;
    int e  = i - ts * E_PER_T;
    int src = ei[(ts * 2) * E_PER_T + e];
    int tar = ei[(ts * 2 + 1) * E_PER_T + e];
    int pos = atomicAdd(&cursor[ts * N_NODES + tar], 1);
    srcbuf[ts * E_PER_T + pos] = src;
}

// ---------------------------------------------------------------------------
// Split-bf16 MFMA projection, ALL 9 (mat x ts) in one dispatch.
// blockIdx.y: ts = y/3, mat = y%3 (0=Q,1=K,2=V).
// ---------------------------------------------------------------------------
__global__ __launch_bounds__(256) void project_all_kernel(
    const float* __restrict__ x,
    const u16* __restrict__ QTh, const u16* __restrict__ QTl, const float* __restrict__ bq,
    const u16* __restrict__ KTh, const u16* __restrict__ KTl, const float* __restrict__ bk,
    const u16* __restrict__ VTh, const u16* __restrict__ VTl, const float* __restrict__ bv,
    u16* __restrict__ Qall, u16* __restrict__ Kall, u16* __restrict__ Vall)
{
    const int p  = blockIdx.y;
    const int ts = p / 3, mat = p - ts * 3;
    const u16 *WTh, *WTl; const float* b; u16* O;
    if (mat == 0)      { WTh = QTh; WTl = QTl; b = bq; O = Qall; }
    else if (mat == 1) { WTh = KTh; WTl = KTl; b = bk; O = Kall; }
    else               { WTh = VTh; WTl = VTl; b = bv; O = Vall; }
    const size_t NHID = (size_t)N_NODES * HID;
    const float* __restrict__ xs = x + (size_t)ts * NHID;
    O += (size_t)ts * NHID;

    __shared__ u16 xhS[64 * 128];
    __shared__ u16 xlS[64 * 128];
    const int tid = threadIdx.x;
    const int n0 = blockIdx.x * 64;

    {   // stage: 4 threads/row, each covers 32 cols; hi/lo split, swizzled
        const int row = tid >> 2, q = tid & 3;
        const int n = n0 + row;
        const float4* xp = (const float4*)(xs + (size_t)n * 128 + q * 32);
        const int sbase = row * 128;
#pragma unroll
        for (int i = 0; i < 4; ++i) {
            float4 a = make_float4(0.f, 0.f, 0.f, 0.f), c = a;
            if (n < N_NODES) { a = xp[2 * i]; c = xp[2 * i + 1]; }
            float vv[8] = {a.x, a.y, a.z, a.w, c.x, c.y, c.z, c.w};
            uint4 uh, ul;
            unsigned* ph = (unsigned*)&uh;
            unsigned* pl = (unsigned*)&ul;
#pragma unroll
            for (int j = 0; j < 4; ++j) {
                u16 h0 = f2bf(vv[2 * j]), h1 = f2bf(vv[2 * j + 1]);
                ph[j] = (unsigned)h0 | ((unsigned)h1 << 16);
                u16 l0 = f2bf(vv[2 * j] - bf2f(h0));
                u16 l1 = f2bf(vv[2 * j + 1] - bf2f(h1));
                pl[j] = (unsigned)l0 | ((unsigned)l1 << 16);
            }
            int ch = (q * 4 + i) ^ (row & 15);
            *(uint4*)&xhS[sbase + ch * 8] = uh;
            *(uint4*)&xlS[sbase + ch * 8] = ul;
        }
    }
    __syncthreads();

    const int lane = tid & 63, w = tid >> 6;
    const int l15 = lane & 15, l4 = lane >> 4;
    f32x4 acc[4][2];
    const f32x4 z4 = {0.f, 0.f, 0.f, 0.f};
#pragma unroll
    for (int m = 0; m < 4; ++m)
#pragma unroll
        for (int n = 0; n < 2; ++n) acc[m][n] = z4;

#pragma unroll
    for (int ks = 0; ks < 4; ++ks) {
        const int ch = (ks * 4 + l4) ^ l15;
        bf16x8 ah[4], al[4];
#pragma unroll
        for (int m = 0; m < 4; ++m) {
            ah[m] = *(const bf16x8*)&xhS[(m * 16 + l15) * 128 + ch * 8];
            al[m] = *(const bf16x8*)&xlS[(m * 16 + l15) * 128 + ch * 8];
        }
        bf16x8 bh[2], bl[2];
#pragma unroll
        for (int n = 0; n < 2; ++n) {
            size_t wo = (size_t)(w * 32 + n * 16 + l15) * 128 + ks * 32 + l4 * 8;
            bh[n] = *(const bf16x8*)(WTh + wo);
            bl[n] = *(const bf16x8*)(WTl + wo);
        }
#pragma unroll
        for (int m = 0; m < 4; ++m)
#pragma unroll
            for (int n = 0; n < 2; ++n) {
                acc[m][n] = mfma16(ah[m], bh[n], acc[m][n]);
                acc[m][n] = mfma16(ah[m], bl[n], acc[m][n]);
                acc[m][n] = mfma16(al[m], bh[n], acc[m][n]);
            }
    }

    // C/D: col = lane&15, row = (lane>>4)*4 + reg
#pragma unroll
    for (int n = 0; n < 2; ++n) {
        int c = w * 32 + n * 16 + l15;
        float bb = b[c];
#pragma unroll
        for (int m = 0; m < 4; ++m)
#pragma unroll
            for (int j = 0; j < 4; ++j) {
                int r = m * 16 + l4 * 4 + j;
                int ng = n0 + r;
                if (ng < N_NODES)
                    O[(size_t)ng * 128 + c] = f2bf(acc[m][n][j] + bb);
            }
    }
}

// ---------------------------------------------------------------------------
// Fused attention, ALL t in one dispatch (blockIdx.y = t_tar).
// One wave per node. Phase A: logits (LDS cache: logit + gsrc=ts*N+src) +
// max/min; Phase B: exp sums; Phase C: flattened 4-way-prefetched V
// accumulate, single hat write. Slow path covers degree > CAP.
// ---------------------------------------------------------------------------
__global__ __launch_bounds__(256) void attn_fused_kernel(
    const u16* __restrict__ Qall, const u16* __restrict__ Kall,
    const u16* __restrict__ Vall,
    const int* __restrict__ offs, const int* __restrict__ srcbuf,
    float* __restrict__ hat_c_all, float* __restrict__ hat_s_all)
{
    __shared__ float logitS[4][CAP][NH];
    __shared__ int   srcS[4][CAP];
    const int t_tar = blockIdx.y;
    const int lane = threadIdx.x & 63;
    const int wave = threadIdx.x >> 6;
    const int node = blockIdx.x * 4 + wave;
    if (node >= N_NODES) return;

    const size_t NHID = (size_t)N_NODES * HID;
    float* __restrict__ hat_c = hat_c_all + (size_t)t_tar * NHID;
    float* __restrict__ hat_s = hat_s_all + (size_t)t_tar * NHID;
    const u16* __restrict__ Qt = Qall + (size_t)t_tar * NHID;
    const int h  = lane & 7;      // phase A/B: head
    const int j8 = lane >> 3;     // phase A/B: edge slot

    float (*lg)[NH] = logitS[wave];
    int* sx = srcS[wave];

    uint4 q0, q1;
    {
        const uint4* qp = (const uint4*)(Qt + (size_t)node * HID + h * DK);
        q0 = qp[0]; q1 = qp[1];
    }

    // ---- Phase A: logits + max/min + LDS cache (gsrc = ts*N + src) ----
    float mx = -1e30f, mn = 1e30f;
    int base = 0;
    for (int ts = 0; ts <= t_tar; ++ts) {
        const int beg = offs[ts * (N_NODES + 1) + node];
        const int end = offs[ts * (N_NODES + 1) + node + 1];
        const u16* __restrict__ K = Kall + (size_t)ts * NHID;
        const int* __restrict__ sb = srcbuf + (size_t)ts * E_PER_T;
        for (int j = beg + j8; j < end; j += 8) {
            int idx = base + (j - beg);
            int src = sb[j];
            const uint4* kp = (const uint4*)(K + (size_t)src * HID + h * DK);
            uint4 k0 = kp[0], k1 = kp[1];
            float s = 0.f;
            const unsigned* pa = (const unsigned*)&q0;
            const unsigned* pb = (const unsigned*)&k0;
#pragma unroll
            for (int i = 0; i < 4; ++i)
                s += __uint_as_float(pa[i] << 16) * __uint_as_float(pb[i] << 16)
                   + __uint_as_float(pa[i] & 0xffff0000u) * __uint_as_float(pb[i] & 0xffff0000u);
            pa = (const unsigned*)&q1; pb = (const unsigned*)&k1;
#pragma unroll
            for (int i = 0; i < 4; ++i)
                s += __uint_as_float(pa[i] << 16) * __uint_as_float(pb[i] << 16)
                   + __uint_as_float(pa[i] & 0xffff0000u) * __uint_as_float(pb[i] & 0xffff0000u);
            s *= 0.25f;  // / sqrt(16)
            mx = fmaxf(mx, s);
            mn = fminf(mn, s);
            if (idx < CAP) { lg[idx][h] = s; if (h == 0) sx[idx] = ts * N_NODES + src; }
        }
        base += end - beg;
    }
    const int dtot = base;
    if (dtot == 0) {
        size_t bidx = (size_t)node * HID + 2 * lane;
        *(float2*)(hat_c + bidx) = make_float2(0.f, 0.f);
        *(float2*)(hat_s + bidx) = make_float2(0.f, 0.f);
        return;
    }
#pragma unroll
    for (int o = 8; o < 64; o <<= 1) {
        mx = fmaxf(mx, __shfl_xor(mx, o));
        mn = fminf(mn, __shfl_xor(mn, o));
    }

    // ---- Phase B: exp sums ----
    float sc = 0.f, ss = 0.f;
    {
        const int nfast = dtot < CAP ? dtot : CAP;
        for (int idx = j8; idx < nfast; idx += 8) {
            float a = lg[idx][h];
            sc += __expf(a - mx);
            ss += __expf(mn - a);
        }
        if (dtot > CAP) {
            int b2 = 0;
            for (int ts = 0; ts <= t_tar; ++ts) {
                const int beg = offs[ts * (N_NODES + 1) + node];
                const int end = offs[ts * (N_NODES + 1) + node + 1];
                const u16* K = Kall + (size_t)ts * NHID;
                const int* sb = srcbuf + (size_t)ts * E_PER_T;
                for (int j = beg + j8; j < end; j += 8) {
                    int idx = b2 + (j - beg);
                    if (idx >= CAP) {
                        int src = sb[j];
                        const uint4* kp = (const uint4*)(K + (size_t)src * HID + h * DK);
                        uint4 k0 = kp[0], k1 = kp[1];
                        float s = 0.f;
                        const unsigned* pa = (const unsigned*)&q0;
                        const unsigned* pb = (const unsigned*)&k0;
#pragma unroll
                        for (int i = 0; i < 4; ++i)
                            s += __uint_as_float(pa[i] << 16) * __uint_as_float(pb[i] << 16)
                               + __uint_as_float(pa[i] & 0xffff0000u) * __uint_as_float(pb[i] & 0xffff0000u);
                        pa = (const unsigned*)&q1; pb = (const unsigned*)&k1;
#pragma unroll
                        for (int i = 0; i < 4; ++i)
                            s += __uint_as_float(pa[i] << 16) * __uint_as_float(pb[i] << 16)
                               + __uint_as_float(pa[i] & 0xffff0000u) * __uint_as_float(pb[i] & 0xffff0000u);
                        s *= 0.25f;
                        sc += __expf(s - mx);
                        ss += __expf(mn - s);
                    }
                }
                b2 += end - beg;
            }
        }
    }
#pragma unroll
    for (int o = 8; o < 64; o <<= 1) {
        sc += __shfl_xor(sc, o);
        ss += __shfl_xor(ss, o);
    }

    // ---- Phase C: V accumulate (lane owns dims 2l,2l+1; head = lane>>3) ----
    const int h2 = lane >> 3;
    const float mc   = __shfl(mx, h2);
    const float mnn  = __shfl(mn, h2);
    const float isc  = 1.f / (__shfl(sc, h2) + 1e-16f);
    const float iss  = 1.f / (__shfl(ss, h2) + 1e-16f);

    float aC0 = 0.f, aC1 = 0.f, aS0 = 0.f, aS1 = 0.f;
    if (dtot <= CAP) {
        // fast: flattened LDS edge list, groups of 4 with prefetched loads
        const int dl = 2 * lane;
        for (int i0 = 0; i0 < dtot; i0 += 4) {
            int i1 = i0 + 1, i2 = i0 + 2, i3 = i0 + 3;
            int k1 = (i1 < dtot) ? i1 : i0;
            int k2 = (i2 < dtot) ? i2 : i0;
            int k3 = (i3 < dtot) ? i3 : i0;
            float a0 = lg[i0][h2], a1 = lg[k1][h2];
            float a2 = lg[k2][h2], a3 = lg[k3][h2];
            int g0 = sx[i0], g1 = sx[k1], g2 = sx[k2], g3 = sx[k3];
            unsigned w0 = *(const unsigned*)(Vall + (size_t)g0 * HID + dl);
            unsigned w1 = *(const unsigned*)(Vall + (size_t)g1 * HID + dl);
            unsigned w2 = *(const unsigned*)(Vall + (size_t)g2 * HID + dl);
            unsigned w3 = *(const unsigned*)(Vall + (size_t)g3 * HID + dl);
            float f1 = (i1 < dtot) ? 1.f : 0.f;
            float f2 = (i2 < dtot) ? 1.f : 0.f;
            float f3 = (i3 < dtot) ? 1.f : 0.f;
            {
                float pc = __expf(a0 - mc) * isc, ps = __expf(mnn - a0) * iss;
                float v0 = __uint_as_float(w0 << 16);
                float v1 = __uint_as_float(w0 & 0xffff0000u);
                aC0 += v0 * pc; aC1 += v1 * pc; aS0 += v0 * ps; aS1 += v1 * ps;
            }
            {
                float pc = __expf(a1 - mc) * isc * f1, ps = __expf(mnn - a1) * iss * f1;
                float v0 = __uint_as_float(w1 << 16);
                float v1 = __uint_as_float(w1 & 0xffff0000u);
                aC0 += v0 * pc; aC1 += v1 * pc; aS0 += v0 * ps; aS1 += v1 * ps;
            }
            {
                float pc = __expf(a2 - mc) * isc * f2, ps = __expf(mnn - a2) * iss * f2;
                float v0 = __uint_as_float(w2 << 16);
                float v1 = __uint_as_float(w2 & 0xffff0000u);
                aC0 += v0 * pc; aC1 += v1 * pc; aS0 += v0 * ps; aS1 += v1 * ps;
            }
            {
                float pc = __expf(a3 - mc) * isc * f3, ps = __expf(mnn - a3) * iss * f3;
                float v0 = __uint_as_float(w3 << 16);
                float v1 = __uint_as_float(w3 & 0xffff0000u);
                aC0 += v0 * pc; aC1 += v1 * pc; aS0 += v0 * ps; aS1 += v1 * ps;
            }
        }
    } else {
        // slow: original CSR walk (rare)
        int b2 = 0;
        for (int ts = 0; ts <= t_tar; ++ts) {
            const int beg = offs[ts * (N_NODES + 1) + node];
            const int end = offs[ts * (N_NODES + 1) + node + 1];
            const int* __restrict__ sb = srcbuf + (size_t)ts * E_PER_T;
            for (int j = beg; j < end; ++j) {
                int idx = b2 + (j - beg);
                float a; size_t gaddr;
                if (idx < CAP) {
                    a = lg[idx][h2];
                    gaddr = (size_t)sx[idx] * HID;
                } else {
                    int src = sb[j];
                    gaddr = ((size_t)ts * N_NODES + src) * HID;
                    unsigned qd = *(const unsigned*)(Qt + (size_t)node * HID + 2 * lane);
                    unsigned kd = *(const unsigned*)(Kall + gaddr + 2 * lane);
                    float p = __uint_as_float(qd << 16) * __uint_as_float(kd << 16)
                            + __uint_as_float(qd & 0xffff0000u) * __uint_as_float(kd & 0xffff0000u);
                    p += __shfl_xor(p, 1);
                    p += __shfl_xor(p, 2);
                    p += __shfl_xor(p, 4);
                    a = p * 0.25f;
                }
                float pc = __expf(a - mc) * isc;
                float ps = __expf(mnn - a) * iss;
                unsigned v2 = *(const unsigned*)(Vall + gaddr + 2 * lane);
                float v0 = __uint_as_float(v2 << 16);
                float v1 = __uint_as_float(v2 & 0xffff0000u);
                aC0 += v0 * pc; aC1 += v1 * pc;
                aS0 += v0 * ps; aS1 += v1 * ps;
            }
            b2 += end - beg;
        }
    }
    size_t bidx = (size_t)node * HID + 2 * lane;
    *(float2*)(hat_c + bidx) = make_float2(aC0, aC1);
    *(float2*)(hat_s + bidx) = make_float2(aS0, aS1);
}

// ---------------------------------------------------------------------------
// FFN via MFMA, ALL t (blockIdx.y = t), branches parallel across waves,
// 32-node tile. Pre-LN rows v[32] in registers; r=a2+b2 -> rS; LN threads
// fold val=v+r in place; streaming phase stores out0/1/2 with fully
// contiguous 1KB-per-wave-instruction float4 stores (no partial sectors).
// ---------------------------------------------------------------------------
__global__ __launch_bounds__(256, 4) void ffn_out_kernel(
    const float* __restrict__ hat_c_all, const float* __restrict__ hat_s_all,
    const float* __restrict__ x,
    const float* __restrict__ ln_s, const float* __restrict__ ln_b,
    const u16* __restrict__ W1T, const float* __restrict__ b1,
    const u16* __restrict__ W2T, const float* __restrict__ b2,
    float* __restrict__ out)
{
    __shared__ char ldsbuf[32768];
    u16* hnS = (u16*)ldsbuf;                 // [2][32*128] bf16 (16 KB)
    u16* chS = (u16*)(ldsbuf + 16384);       // [2][2][32*64] bf16 (16 KB)
    float* rS = (float*)ldsbuf;              // [2][32][128] f32 overlay (32 KB)

    const int t_tar = blockIdx.y;
    const int n0 = blockIdx.x * 32;
    const int tid = threadIdx.x;
    const size_t NHID = (size_t)N_NODES * HID;
    const float* __restrict__ hat_c = hat_c_all + (size_t)t_tar * NHID;
    const float* __restrict__ hat_s = hat_s_all + (size_t)t_tar * NHID;
    const float* __restrict__ xt = x + (size_t)t_tar * NHID;
    const size_t TS = (size_t)T_WIN * N_NODES * HID;
    const size_t outbase = (size_t)t_tar * NHID;

    const int lane = tid & 63;
    const int wave = tid >> 6;
    const int br   = wave >> 1;          // GEMM branch: 0 causal, 1 spurious
    const int wv   = wave & 1;           // wave-within-branch
    const int l15 = lane & 15, l4 = lane >> 4;
    const f32x4 z4 = {0.f, 0.f, 0.f, 0.f};

    // LN mapping: brL = tid>>7 (== br), 4 threads/row, 32 cols each
    const int brL = tid >> 7;
    const int rowL = (tid & 127) >> 2, qL = tid & 3;
    const int nL = n0 + rowL;
    const float* __restrict__ hatL = brL ? hat_s : hat_c;

    float v[32];   // pre-LN row segment (hat [+x]) -- LIVE through GEMMs

    // ---- LayerNorm ----
    {
        float s = 0.f, s2 = 0.f;
        if (nL < N_NODES) {
            const float4* hp = (const float4*)(hatL + (size_t)nL * 128 + qL * 32);
            const float4* xp = (const float4*)(xt + (size_t)nL * 128 + qL * 32);
#pragma unroll
            for (int i = 0; i < 8; ++i) {
                float4 a = hp[i];
                if (brL == 0) {
                    float4 bx = xp[i];
                    a.x += bx.x; a.y += bx.y; a.z += bx.z; a.w += bx.w;
                }
                v[4 * i] = a.x; v[4 * i + 1] = a.y;
                v[4 * i + 2] = a.z; v[4 * i + 3] = a.w;
                s  += a.x + a.y + a.z + a.w;
                s2 += a.x * a.x + a.y * a.y + a.z * a.z + a.w * a.w;
            }
        } else {
#pragma unroll
            for (int i = 0; i < 32; ++i) v[i] = 0.f;
        }
        s  += __shfl_xor(s, 1);  s  += __shfl_xor(s, 2);
        s2 += __shfl_xor(s2, 1); s2 += __shfl_xor(s2, 2);
        float mu  = s * (1.f / 128.f);
        float var = s2 * (1.f / 128.f) - mu * mu;
        float rstd = rsqrtf(var + 1e-5f);
        const int sbase = brL * 4096 + rowL * 128;
#pragma unroll
        for (int i = 0; i < 4; ++i) {
            uint4 uh; unsigned* ph = (unsigned*)&uh;
#pragma unroll
            for (int j = 0; j < 4; ++j) {
                int c0 = qL * 32 + i * 8 + 2 * j;
                float h0 = (v[i * 8 + 2 * j]     - mu) * rstd * ln_s[c0]     + ln_b[c0];
                float h1 = (v[i * 8 + 2 * j + 1] - mu) * rstd * ln_s[c0 + 1] + ln_b[c0 + 1];
                if (nL >= N_NODES) { h0 = 0.f; h1 = 0.f; }
                ph[j] = (unsigned)f2bf(h0) | ((unsigned)f2bf(h1) << 16);
            }
            int ch = (qL * 4 + i) ^ (rowL & 15);
            *(uint4*)&hnS[sbase + ch * 8] = uh;
        }
    }
    __syncthreads();

    // ---- chunked GEMM1 -> GELU -> GEMM2 (K-fused, dbuf chS) ----
    f32x4 a2[2][4];
#pragma unroll
    for (int m = 0; m < 2; ++m)
#pragma unroll
        for (int n = 0; n < 4; ++n) a2[m][n] = z4;

#pragma unroll
    for (int cc = 0; cc < 4; ++cc) {
        f32x4 a1[2][2];
#pragma unroll
        for (int m = 0; m < 2; ++m)
#pragma unroll
            for (int n = 0; n < 2; ++n) a1[m][n] = z4;
#pragma unroll
        for (int ks = 0; ks < 4; ++ks) {
            const int ch = (ks * 4 + l4) ^ l15;
            bf16x8 af[2];
#pragma unroll
            for (int m = 0; m < 2; ++m)
                af[m] = *(const bf16x8*)&hnS[br * 4096 + (m * 16 + l15) * 128 + ch * 8];
#pragma unroll
            for (int n = 0; n < 2; ++n) {
                bf16x8 bfr = *(const bf16x8*)(W1T
                    + (size_t)(cc * 64 + wv * 32 + n * 16 + l15) * 128 + ks * 32 + l4 * 8);
#pragma unroll
                for (int m = 0; m < 2; ++m)
                    a1[m][n] = mfma16(af[m], bfr, a1[m][n]);
            }
        }
        // bias + exact GELU -> swizzled bf16 chunk tile
        u16* chw = chS + ((cc & 1) * 2 + br) * (32 * 64);
#pragma unroll
        for (int n = 0; n < 2; ++n) {
            int cl = wv * 32 + n * 16 + l15;        // local col 0..63
            float bb = b1[cc * 64 + cl];
#pragma unroll
            for (int m = 0; m < 2; ++m)
#pragma unroll
                for (int j = 0; j < 4; ++j) {
                    int r = m * 16 + l4 * 4 + j;
                    float zz = a1[m][n][j] + bb;
                    float g = 0.5f * zz * (1.f + erff(zz * 0.70710678118654752f));
                    chw[r * 64 + (((cl >> 3) ^ (r & 7)) * 8) + (cl & 7)] = f2bf(g);
                }
        }
        __syncthreads();
        // GEMM2 partial: K-slice cc*64..cc*64+63
        const u16* chr = chS + ((cc & 1) * 2 + br) * (32 * 64);
#pragma unroll
        for (int ks2 = 0; ks2 < 2; ++ks2) {
            const int ch8 = (ks2 * 4 + l4) ^ (l15 & 7);
            bf16x8 af[2];
#pragma unroll
            for (int m = 0; m < 2; ++m)
                af[m] = *(const bf16x8*)&chr[(m * 16 + l15) * 64 + ch8 * 8];
#pragma unroll
            for (int n = 0; n < 4; ++n) {
                bf16x8 bfr = *(const bf16x8*)(W2T
                    + (size_t)(wv * 64 + n * 16 + l15) * 256 + cc * 64 + ks2 * 32 + l4 * 8);
#pragma unroll
                for (int m = 0; m < 2; ++m)
                    a2[m][n] = mfma16(af[m], bfr, a2[m][n]);
            }
        }
    }
    __syncthreads();   // hnS + chS now dead -> rS overlay is safe

    // ---- r = a2 + b2 -> LDS (XOR-swizzled fp32) ----
#pragma unroll
    for (int n = 0; n < 4; ++n) {
        int c = wv * 64 + n * 16 + l15;
        float bb = b2[c];
#pragma unroll
        for (int m = 0; m < 2; ++m)
#pragma unroll
            for (int j = 0; j < 4; ++j) {
                int r = m * 16 + l4 * 4 + j;
                rS[br * 4096 + r * 128 + (c ^ ((r & 7) << 2))] = a2[m][n][j] + bb;
            }
    }
    __syncthreads();

    // ---- LN threads: fold val = v + r into rS in place ----
    {
        const int swzL = (rowL & 7) << 2;
#pragma unroll
        for (int i = 0; i < 8; ++i) {
            int coff = brL * 4096 + rowL * 128 + ((qL * 32 + i * 4) ^ swzL);
            float4 rv = *(const float4*)&rS[coff];
            rv.x += v[4 * i];     rv.y += v[4 * i + 1];
            rv.z += v[4 * i + 2]; rv.w += v[4 * i + 3];
            *(float4*)&rS[coff] = rv;
        }
    }
    __syncthreads();

    // ---- streaming stores: fully contiguous (1KB/wave/instr) ----
    {
        const int nrows = N_NODES - n0;   // valid rows in tile (<=32 means tail)
        float* o0 = out + outbase + (size_t)n0 * 128;
        float* o1 = out + TS + outbase + (size_t)n0 * 128;
        float* o2 = out + 2 * TS + outbase + (size_t)n0 * 128;
#pragma unroll
        for (int it = 0; it < 4; ++it) {
            int lin = it * 1024 + tid * 4;
            int row = lin >> 7, col = lin & 127;
            int sw  = col ^ ((row & 7) << 2);
            if (row < nrows) {
                float4 cv = *(const float4*)&rS[row * 128 + sw];
                float4 sv = *(const float4*)&rS[4096 + row * 128 + sw];
                *(float4*)&o1[lin] = cv;
                *(float4*)&o2[lin] = sv;
                *(float4*)&o0[lin] = make_float4(cv.x + sv.x, cv.y + sv.y,
                                                 cv.z + sv.z, cv.w + sv.w);
            }
        }
    }
}

extern "C" void kernel_launch(void* const* d_in, const int* in_sizes, int n_in,
                              void* d_out, int out_size, void* d_ws, size_t ws_size,
                              hipStream_t stream) {
    const float* x    = (const float*)d_in[0];
    const int*   ei   = (const int*)  d_in[1];
    const float* Wq   = (const float*)d_in[2];
    const float* bq   = (const float*)d_in[3];
    const float* Wk   = (const float*)d_in[4];
    const float* bk   = (const float*)d_in[5];
    const float* Wv   = (const float*)d_in[6];
    const float* bv   = (const float*)d_in[7];
    const float* ln_s = (const float*)d_in[8];
    const float* ln_b = (const float*)d_in[9];
    const float* W1   = (const float*)d_in[10];
    const float* b1   = (const float*)d_in[11];
    const float* W2   = (const float*)d_in[12];
    const float* b2   = (const float*)d_in[13];
    float* out = (float*)d_out;

    // ---- Workspace layout (~274 MB) ----
    const size_t NHID = (size_t)N_NODES * HID;  // 6,400,000
    char* p = (char*)d_ws;
    auto alloc = [&p](size_t bytes) -> void* {
        void* r = (void*)p;
        p += (bytes + 255) & ~(size_t)255;
        return r;
    };
    float* hat_c = (float*)alloc(3 * NHID * 4);   // [t][N][HID]
    float* hat_s = (float*)alloc(3 * NHID * 4);
    int* offs    = (int*)alloc((size_t)T_WIN * (N_NODES + 1) * 4);
    int* cursor  = (int*)alloc((size_t)T_WIN * N_NODES * 4);
    int* srcbuf  = (int*)alloc((size_t)T_WIN * E_PER_T * 4);
    u16* WqTh = (u16*)alloc(128 * 128 * 2);
    u16* WqTl = (u16*)alloc(128 * 128 * 2);
    u16* WkTh = (u16*)alloc(128 * 128 * 2);
    u16* WkTl = (u16*)alloc(128 * 128 * 2);
    u16* WvTh = (u16*)alloc(128 * 128 * 2);
    u16* WvTl = (u16*)alloc(128 * 128 * 2);
    u16* W1T  = (u16*)alloc(128 * 256 * 2);
    u16* W2T  = (u16*)alloc(256 * 128 * 2);
    u16* Qall = (u16*)alloc(3 * NHID * 2);
    u16* Kall = (u16*)alloc(3 * NHID * 2);
    u16* Vall = (u16*)alloc(3 * NHID * 2);

    const int PROJ_BLOCKS = (N_NODES + 63) / 64;          // 782
    const int FFN_BLOCKS  = (N_NODES + 31) / 32;          // 1563
    const int NODE_BLOCKS = (N_NODES + 3) / 4;            // 12500
    const int TN_BLOCKS   = (T_WIN * N_NODES + 255) / 256;
    const int TE_BLOCKS   = (T_WIN * E_PER_T + 255) / 256;

    // ---- weight prep (one dispatch) ----
    {
        dim3 wg(128, 5);
        wprep_kernel<<<wg, 256, 0, stream>>>(
            Wq, Wk, Wv, W1, W2,
            WqTh, WqTl, WkTh, WkTl, WvTh, WvTl, W1T, W2T);
    }

    // ---- CSR build ----
    zero_counts_kernel<<<TN_BLOCKS, 256, 0, stream>>>(cursor);
    hist_kernel<<<TE_BLOCKS, 256, 0, stream>>>(ei, cursor);
    scan_kernel<<<T_WIN, 1024, 0, stream>>>(cursor, offs);
    copy_cursor_kernel<<<TN_BLOCKS, 256, 0, stream>>>(offs, cursor);
    fill_kernel<<<TE_BLOCKS, 256, 0, stream>>>(ei, cursor, srcbuf);

    // ---- all projections (Q/K/V x 3 ts) in one dispatch ----
    {
        dim3 pg(PROJ_BLOCKS, 9);
        project_all_kernel<<<pg, 256, 0, stream>>>(
            x, WqTh, WqTl, bq, WkTh, WkTl, bk, WvTh, WvTl, bv,
            Qall, Kall, Vall);
    }

    // ---- attention, all t in one dispatch ----
    {
        dim3 ag(NODE_BLOCKS, T_WIN);
        attn_fused_kernel<<<ag, 256, 0, stream>>>(
            Qall, Kall, Vall, offs, srcbuf, hat_c, hat_s);
    }

    // ---- FFN + output, all t in one dispatch ----
    {
        dim3 fg(FFN_BLOCKS, T_WIN);
        ffn_out_kernel<<<fg, 256, 0, stream>>>(
            hat_c, hat_s, x, ln_s, ln_b, W1T, b1, W2T, b2, out);
    }
}